// Round 2
// baseline (1992.966 us; speedup 1.0000x reference)
//
#include <hip/hip_runtime.h>
#include <hip/hip_bf16.h>
#include <math.h>

#define BDIM 1024
#define TDIM 4096
#define BT   16384   // B*T
#define KEXPN 8
#define RRANK 64
#define KR   512     // KEXPN*RRANK
#define KRE  544     // extended K (512 + 8 bias cols + 24 zero pad)
#define NCH  64
#define TC   64      // T per chunk (NCH*TC == TDIM)

typedef __attribute__((ext_vector_type(8))) short bf16x8;
typedef __attribute__((ext_vector_type(4))) float f32x4;

// ---------------- elementwise conversion f32 -> bf16 (vectorized x4) ----------------
__global__ __launch_bounds__(256) void cvt_bf16_kernel(const float* __restrict__ in,
    __hip_bfloat16* __restrict__ out, long n4) {
  long id = (long)blockIdx.x * 256 + threadIdx.x;
  if (id >= n4) return;
  f32x4 v = ((const f32x4*)in)[id];
  long i = id * 4;
  out[i + 0] = __float2bfloat16(v[0]);
  out[i + 1] = __float2bfloat16(v[1]);
  out[i + 2] = __float2bfloat16(v[2]);
  out[i + 3] = __float2bfloat16(v[3]);
}

// ---------------- transpose-pack: out[e][d] = in[d][e], f32 -> bf16, D x D ----------------
__global__ __launch_bounds__(256) void transpose_pack_kernel(const float* __restrict__ in,
    __hip_bfloat16* __restrict__ out) {
  int id = blockIdx.x * 256 + threadIdx.x;   // 0 .. D*D
  if (id >= BDIM * BDIM) return;
  int d = id & (BDIM - 1);
  int e = id >> 10;
  out[(size_t)e * BDIM + d] = __float2bfloat16(in[(size_t)d * BDIM + e]);
}

// ---------------- pack V (K,D,R) -> Vmat[(k*64+r)][d] bf16 ----------------
__global__ __launch_bounds__(256) void pack_vmat_kernel(const float* __restrict__ V,
    __hip_bfloat16* __restrict__ out) {
  int id = blockIdx.x * 256 + threadIdx.x;     // 0 .. KR*BDIM
  if (id >= KR * BDIM) return;
  int d = id & (BDIM - 1);
  int kr = id >> 10;
  int k = kr >> 6, r = kr & 63;
  out[(size_t)kr * BDIM + d] = __float2bfloat16(V[((size_t)k * BDIM + d) * RRANK + r]);
}

// ---------------- pack U (K,D,R) + b (K,D) -> Ut[d][c] bf16, c in [0,544) ----------------
__global__ __launch_bounds__(256) void pack_ut_kernel(const float* __restrict__ U,
    const float* __restrict__ bvec, __hip_bfloat16* __restrict__ out) {
  int id = blockIdx.x * 256 + threadIdx.x;     // 0 .. BDIM*KRE
  if (id >= BDIM * KRE) return;
  int d = id / KRE;
  int c = id - d * KRE;
  float v;
  if (c < KR) {
    int k = c >> 6, r = c & 63;
    v = U[((size_t)k * BDIM + d) * RRANK + r];
  } else if (c < KR + KEXPN) {
    v = bvec[(size_t)(c - KR) * BDIM + d];
  } else {
    v = 0.0f;
  }
  out[(size_t)d * KRE + c] = __float2bfloat16(v);
}

// ---------------- generic GEMM: C(MxN) = A(MxK) * B(NxK)^T, bf16 in, f32 acc ----------------
// EPI: 0 = store f32, 1 = store bf16, 2 = bias + exact GELU -> bf16, 3 = accumulate into f32 C
template<int EPI>
__global__ __launch_bounds__(256) void gemm_nt(const __hip_bfloat16* __restrict__ A,
    const __hip_bfloat16* __restrict__ B, void* __restrict__ Cv,
    const float* __restrict__ bias, int M, int N, int Kd) {
  int l  = threadIdx.x & 63;
  int w  = threadIdx.x >> 6;
  int lr = l & 15;
  int lk = l >> 4;
  int row0 = blockIdx.y * 64 + (w >> 1) * 32;
  int col0 = blockIdx.x * 64 + (w & 1) * 32;
  const short* As = (const short*)A;
  const short* Bs = (const short*)B;
  f32x4 acc[2][2] = {};
  for (int k0 = 0; k0 < Kd; k0 += 32) {
    bf16x8 a0 = *(const bf16x8*)(As + (size_t)(row0 + lr) * Kd + k0 + lk * 8);
    bf16x8 a1 = *(const bf16x8*)(As + (size_t)(row0 + 16 + lr) * Kd + k0 + lk * 8);
    bf16x8 b0 = *(const bf16x8*)(Bs + (size_t)(col0 + lr) * Kd + k0 + lk * 8);
    bf16x8 b1 = *(const bf16x8*)(Bs + (size_t)(col0 + 16 + lr) * Kd + k0 + lk * 8);
    acc[0][0] = __builtin_amdgcn_mfma_f32_16x16x32_bf16(a0, b0, acc[0][0], 0, 0, 0);
    acc[0][1] = __builtin_amdgcn_mfma_f32_16x16x32_bf16(a0, b1, acc[0][1], 0, 0, 0);
    acc[1][0] = __builtin_amdgcn_mfma_f32_16x16x32_bf16(a1, b0, acc[1][0], 0, 0, 0);
    acc[1][1] = __builtin_amdgcn_mfma_f32_16x16x32_bf16(a1, b1, acc[1][1], 0, 0, 0);
  }
  #pragma unroll
  for (int i = 0; i < 2; i++)
    #pragma unroll
    for (int j = 0; j < 2; j++)
      #pragma unroll
      for (int g = 0; g < 4; g++) {
        int r = row0 + i * 16 + lk * 4 + g;
        int c = col0 + j * 16 + lr;
        size_t idx = (size_t)r * N + c;
        float v = acc[i][j][g];
        if (EPI == 0) {
          ((float*)Cv)[idx] = v;
        } else if (EPI == 1) {
          ((__hip_bfloat16*)Cv)[idx] = __float2bfloat16(v);
        } else if (EPI == 2) {
          float xv = v + bias[c];
          float gl = 0.5f * xv * (1.0f + erff(xv * 0.70710678118654752f));
          ((__hip_bfloat16*)Cv)[idx] = __float2bfloat16(gl);
        } else {
          ((float*)Cv)[idx] += v;
        }
      }
}

// ---------------- router: logits = H @ w2^T + b2 + ebias; softmax over 8 (H is bf16) ----------------
__global__ __launch_bounds__(256) void router_kernel(const __hip_bfloat16* __restrict__ H,
    const float* __restrict__ w2, const float* __restrict__ b2,
    const float* __restrict__ ebias, float* __restrict__ wgt) {
  int wv = threadIdx.x >> 6;
  int l  = threadIdx.x & 63;
  int row = blockIdx.x * 4 + wv;
  if (row >= BT) return;
  float acc[KEXPN] = {};
  for (int i = 0; i < BDIM / 64; i++) {
    int h = i * 64 + l;
    float hv = __bfloat162float(H[(size_t)row * BDIM + h]);
    #pragma unroll
    for (int k = 0; k < KEXPN; k++) acc[k] += hv * w2[k * BDIM + h];
  }
  #pragma unroll
  for (int k = 0; k < KEXPN; k++)
    for (int off = 32; off; off >>= 1) acc[k] += __shfl_down(acc[k], off);
  if (l == 0) {
    float lg[KEXPN];
    float mx = -1e30f;
    #pragma unroll
    for (int k = 0; k < KEXPN; k++) { lg[k] = acc[k] + b2[k] + ebias[k]; mx = fmaxf(mx, lg[k]); }
    float s = 0.0f;
    #pragma unroll
    for (int k = 0; k < KEXPN; k++) { lg[k] = expf(lg[k] - mx); s += lg[k]; }
    float inv = 1.0f / s;
    #pragma unroll
    for (int k = 0; k < KEXPN; k++) wgt[(size_t)row * KEXPN + k] = lg[k] * inv;
  }
}

// ---------------- cumsum phase 1: per-chunk sums ----------------
__global__ __launch_bounds__(512) void chunksum_kernel(const float* __restrict__ yW,
    float* __restrict__ S) {
  int kr = threadIdx.x;       // 0..511
  int ch = blockIdx.x;        // 0..63
  int b  = blockIdx.y;        // 0..3
  size_t base = ((size_t)b * TDIM + ch * TC) * KR + kr;
  float s = 0.0f;
  for (int t = 0; t < TC; t++) s += yW[base + (size_t)t * KR];
  S[((size_t)b * NCH + ch) * KR + kr] = s;
}

// ---------------- cumsum phase 2: exclusive scan of chunk sums (in place) ----------------
__global__ __launch_bounds__(512) void scan_chunks_kernel(float* __restrict__ S) {
  int kr = threadIdx.x;
  int b  = blockIdx.x;
  float run = 0.0f;
  for (int ch = 0; ch < NCH; ch++) {
    size_t i = ((size_t)b * NCH + ch) * KR + kr;
    float v = S[i];
    S[i] = run;
    run += v;
  }
}

// ---------------- cumsum phase 3 + combine: P = bf16(xV * cum(yW) * w * scale) ----------------
__global__ __launch_bounds__(512) void combine_kernel(const float* __restrict__ yW,
    const float* __restrict__ S, const float* __restrict__ xV,
    const float* __restrict__ wgt, const float* __restrict__ alphaPtr, int useAlpha,
    __hip_bfloat16* __restrict__ P) {
  int kr = threadIdx.x;
  int ch = blockIdx.x;
  int b  = blockIdx.y;
  int k  = kr >> 6;
  float scale = useAlpha ? alphaPtr[0] : 1.0f;
  float run = S[((size_t)b * NCH + ch) * KR + kr];
  for (int t0 = 0; t0 < TC; t0++) {
    size_t row = (size_t)b * TDIM + ch * TC + t0;
    run += yW[row * KR + kr];
    float p = xV[row * KR + kr] * run * wgt[row * KEXPN + k] * scale;
    P[row * KRE + kr] = __float2bfloat16(p);
  }
}

// ---------------- fill extension columns of P: weights (scaled) then zeros ----------------
__global__ __launch_bounds__(256) void extfill_kernel(__hip_bfloat16* __restrict__ P,
    const float* __restrict__ wgt, const float* __restrict__ alphaPtr, int useAlpha) {
  int id = blockIdx.x * 256 + threadIdx.x;   // BT*32
  int row = id >> 5, j = id & 31;
  if (row >= BT) return;
  float scale = useAlpha ? alphaPtr[0] : 1.0f;
  float v = (j < KEXPN) ? wgt[(size_t)row * KEXPN + j] * scale : 0.0f;
  P[(size_t)row * KRE + KR + j] = __float2bfloat16(v);
}

// ---------------- divide by n_valid and convert to bf16 ----------------
__global__ __launch_bounds__(256) void div_kernel(const float* __restrict__ F,
    __hip_bfloat16* __restrict__ Z) {
  long id = (long)blockIdx.x * 256 + threadIdx.x;   // BT*BDIM/4
  f32x4 v = ((const f32x4*)F)[id];
  long e = id * 4;
  int row = (int)(e >> 10);
  int t = row & (TDIM - 1);
  float s = 1.0f / (float)(t + 1);
  Z[e + 0] = __float2bfloat16(v[0] * s);
  Z[e + 1] = __float2bfloat16(v[1] * s);
  Z[e + 2] = __float2bfloat16(v[2] * s);
  Z[e + 3] = __float2bfloat16(v[3] * s);
}

// ---------------- sentinel: encode required workspace MB into d_out ----------------
__global__ __launch_bounds__(256) void fill_kernel(float* __restrict__ out, long n, float val) {
  long id = (long)blockIdx.x * 256 + threadIdx.x;
  if (id < n) out[id] = val;
}

extern "C" void kernel_launch(void* const* d_in, const int* in_sizes, int n_in,
                              void* d_out, int out_size, void* d_ws, size_t ws_size,
                              hipStream_t stream) {
  const float* x        = (const float*)d_in[0];
  const float* W_Q      = (const float*)d_in[1];
  const float* W_K      = (const float*)d_in[2];
  const float* W_O      = (const float*)d_in[3];
  const float* W_inv    = (const float*)d_in[4];
  const float* V_fwd    = (const float*)d_in[5];
  const float* W_fwd    = (const float*)d_in[6];
  const float* U_fwd    = (const float*)d_in[7];
  const float* b_fwd    = (const float*)d_in[8];
  const float* V_inv    = (const float*)d_in[9];
  const float* W_inv_e  = (const float*)d_in[10];
  const float* U_inv    = (const float*)d_in[11];
  const float* b_inv    = (const float*)d_in[12];
  const float* rw1      = (const float*)d_in[13];
  const float* rb1      = (const float*)d_in[14];
  const float* rw2      = (const float*)d_in[15];
  const float* rb2      = (const float*)d_in[16];
  const float* alphaPtr = (const float*)d_in[17];
  const float* ebias    = (const float*)d_in[18];

  char* ws = (char*)d_ws;
  size_t off = 0;
  auto alloc = [&](size_t sz) -> void* {
    void* p = ws + off;
    off += (sz + 255) & ~(size_t)255;
    return p;
  };

  // ---- small weight buffers (~25 MB) ----
  void* wq    = alloc((size_t)BDIM * BDIM * 2);
  void* wk    = alloc((size_t)BDIM * BDIM * 2);
  void* wo    = alloc((size_t)BDIM * BDIM * 2);
  void* w1    = alloc((size_t)BDIM * BDIM * 2);
  void* winvT = alloc((size_t)BDIM * BDIM * 2);   // W_inv transposed: [e][d] = W_inv[d][e]
  void* w1i   = alloc((size_t)BDIM * BDIM * 2);   // w1 @ W_inv
  void* vm_f  = alloc((size_t)KR * BDIM * 2);     // packed V_fwd
  void* wm_f  = alloc((size_t)KR * BDIM * 2);     // packed W_fwd
  void* vm_ie = alloc((size_t)KR * BDIM * 2);     // packed W_inv_exp
  void* vm_i  = alloc((size_t)KR * BDIM * 2);     // packed V_inv
  void* Gq    = alloc((size_t)KR * BDIM * 2);     // packed(W_inv_exp) @ W_inv  (xV_inv weights)
  void* Gk    = alloc((size_t)KR * BDIM * 2);     // packed(V_inv)     @ W_inv  (yW_inv weights)
  void* ut_f  = alloc((size_t)BDIM * KRE * 2);
  void* ut_i  = alloc((size_t)BDIM * KRE * 2);
  void* wgt_f = alloc((size_t)BT * KEXPN * 4);
  void* wgt_i = alloc((size_t)BT * KEXPN * 4);
  void* S     = alloc((size_t)4 * NCH * KR * 4);
  // ---- big slots (5 x 33.5 MB = 168 MB) ----
  void* s_Q   = alloc((size_t)BT * BDIM * 2);     // Q bf16; later (with s_K) F f32
  void* s_K   = alloc((size_t)BT * BDIM * 2);     // K bf16  (adjacent to s_Q)
  void* s_x   = alloc((size_t)BT * BDIM * 2);     // x bf16; later H bf16
  void* s_xV  = alloc((size_t)BT * KR * 4);       // xV f32;  later Zb bf16
  void* s_yW  = alloc((size_t)BT * KR * 4);       // yW f32
  void* F  = s_Q;   // 67.1 MB f32 spans s_Q+s_K (both dead by then, contiguous)
  void* H  = s_x;   // 33.5 MB bf16 after x is dead
  void* Zb = s_xV;  // 33.5 MB bf16 after xV is dead

  if (off > ws_size) {
    // Encode required MB into the output so the bench reports it as absmax.
    fill_kernel<<<dim3((unsigned)((out_size + 255) / 256)), 256, 0, stream>>>(
        (float*)d_out, (long)out_size, (float)(off >> 20));
    return;
  }

  auto cvt = [&](const float* in, void* out, long n) {
    long n4 = n / 4;
    cvt_bf16_kernel<<<dim3((unsigned)((n4 + 255) / 256)), dim3(256), 0, stream>>>(
        in, (__hip_bfloat16*)out, n4);
  };
  auto gemm = [&](const void* A, const void* Bm, void* C, int M, int N, int Kd,
                  int epi, const float* bias) {
    dim3 g(N / 64, M / 64);
    if (epi == 0)      gemm_nt<0><<<g, 256, 0, stream>>>((const __hip_bfloat16*)A, (const __hip_bfloat16*)Bm, C, bias, M, N, Kd);
    else if (epi == 1) gemm_nt<1><<<g, 256, 0, stream>>>((const __hip_bfloat16*)A, (const __hip_bfloat16*)Bm, C, bias, M, N, Kd);
    else if (epi == 2) gemm_nt<2><<<g, 256, 0, stream>>>((const __hip_bfloat16*)A, (const __hip_bfloat16*)Bm, C, bias, M, N, Kd);
    else               gemm_nt<3><<<g, 256, 0, stream>>>((const __hip_bfloat16*)A, (const __hip_bfloat16*)Bm, C, bias, M, N, Kd);
  };

  // ---- conversions & packing ----
  cvt(x,   s_x, (long)BT * BDIM);
  cvt(W_Q, wq,  (long)BDIM * BDIM);
  cvt(W_K, wk,  (long)BDIM * BDIM);
  cvt(W_O, wo,  (long)BDIM * BDIM);
  cvt(rw1, w1,  (long)BDIM * BDIM);
  {
    dim3 gt((BDIM * BDIM + 255) / 256);
    transpose_pack_kernel<<<gt, 256, 0, stream>>>(W_inv, (__hip_bfloat16*)winvT);
    dim3 g((KR * BDIM + 255) / 256);
    pack_vmat_kernel<<<g, 256, 0, stream>>>(V_fwd,   (__hip_bfloat16*)vm_f);
    pack_vmat_kernel<<<g, 256, 0, stream>>>(W_fwd,   (__hip_bfloat16*)wm_f);
    pack_vmat_kernel<<<g, 256, 0, stream>>>(W_inv_e, (__hip_bfloat16*)vm_ie);
    pack_vmat_kernel<<<g, 256, 0, stream>>>(V_inv,   (__hip_bfloat16*)vm_i);
    dim3 gu((BDIM * KRE + 255) / 256);
    pack_ut_kernel<<<gu, 256, 0, stream>>>(U_fwd, b_fwd, (__hip_bfloat16*)ut_f);
    pack_ut_kernel<<<gu, 256, 0, stream>>>(U_inv, b_inv, (__hip_bfloat16*)ut_i);
  }

  // ---- fold W_inv into inv-branch weights (tiny GEMMs) ----
  // w1i[h][e]  = sum_d w1[h][d]  * W_inv[d][e]   -> H_inv = gelu(Q @ w1i^T + b1)
  // Gq[kr][e]  = sum_d Wie[k,d,r]* W_inv[d][e]   -> xV_inv = Q @ Gq^T
  // Gk[kr][e]  = sum_d Vin[k,d,r]* W_inv[d][e]   -> yW_inv = K @ Gk^T
  gemm(w1,    winvT, w1i, BDIM, BDIM, BDIM, 1, nullptr);
  gemm(vm_ie, winvT, Gq,  KR,   BDIM, BDIM, 1, nullptr);
  gemm(vm_i,  winvT, Gk,  KR,   BDIM, BDIM, 1, nullptr);

  // ---- projections ----
  gemm(s_x, wq, s_Q, BT, BDIM, BDIM, 1, nullptr);   // Q
  gemm(s_x, wk, s_K, BT, BDIM, BDIM, 1, nullptr);   // K   (x dead after this)

  dim3 gch(NCH, 4);

  // ---- forward branch ----
  gemm(s_Q, w1, H, BT, BDIM, BDIM, 2, rb1);         // H = gelu(Q w1^T + b1), bf16 (overlays x)
  router_kernel<<<dim3(BT / 4), 256, 0, stream>>>((const __hip_bfloat16*)H, rw2, rb2, ebias, (float*)wgt_f);
  gemm(s_Q, vm_f, s_xV, BT, KR, BDIM, 0, nullptr);  // xV = Q V_fwd
  gemm(s_K, wm_f, s_yW, BT, KR, BDIM, 0, nullptr);  // yW = K W_fwd
  chunksum_kernel<<<gch, 512, 0, stream>>>((const float*)s_yW, (float*)S);
  scan_chunks_kernel<<<dim3(4), 512, 0, stream>>>((float*)S);
  void* Pf = s_yW;  // NOTE: cannot overlay (combine reads yW) — keep separate:
  // (allocate Pf/Pi after the big slots to keep lifetimes simple)
  Pf = alloc((size_t)BT * KRE * 2);
  void* Pi = alloc((size_t)BT * KRE * 2);
  if (off > ws_size) {
    fill_kernel<<<dim3((unsigned)((out_size + 255) / 256)), 256, 0, stream>>>(
        (float*)d_out, (long)out_size, (float)(off >> 20));
    return;
  }
  combine_kernel<<<gch, 512, 0, stream>>>((const float*)s_yW, (const float*)S,
      (const float*)s_xV, (const float*)wgt_f, alphaPtr, 0, (__hip_bfloat16*)Pf);
  extfill_kernel<<<dim3(BT * 32 / 256), 256, 0, stream>>>((__hip_bfloat16*)Pf,
      (const float*)wgt_f, alphaPtr, 0);

  // ---- inverse branch (reads Q,K with folded weights) ----
  gemm(s_Q, w1i, H, BT, BDIM, BDIM, 2, rb1);
  router_kernel<<<dim3(BT / 4), 256, 0, stream>>>((const __hip_bfloat16*)H, rw2, rb2, ebias, (float*)wgt_i);
  gemm(s_Q, Gq, s_xV, BT, KR, BDIM, 0, nullptr);    // xV_inv
  gemm(s_K, Gk, s_yW, BT, KR, BDIM, 0, nullptr);    // yW_inv   (Q,K dead after this)
  chunksum_kernel<<<gch, 512, 0, stream>>>((const float*)s_yW, (float*)S);
  scan_chunks_kernel<<<dim3(4), 512, 0, stream>>>((float*)S);
  combine_kernel<<<gch, 512, 0, stream>>>((const float*)s_yW, (const float*)S,
      (const float*)s_xV, (const float*)wgt_i, alphaPtr, 1, (__hip_bfloat16*)Pi);
  extfill_kernel<<<dim3(BT * 32 / 256), 256, 0, stream>>>((__hip_bfloat16*)Pi,
      (const float*)wgt_i, alphaPtr, 1);

  // ---- U projections (+bias via extended K), fwd + alpha*inv accumulated into F ----
  gemm(Pf, ut_f, F, BT, BDIM, KRE, 0, nullptr);     // F overlays s_Q+s_K (dead)
  gemm(Pi, ut_i, F, BT, BDIM, KRE, 3, nullptr);

  // ---- divide by n_valid, convert to bf16 ----
  div_kernel<<<dim3(BT * BDIM / 4 / 256), 256, 0, stream>>>((const float*)F, (__hip_bfloat16*)Zb);

  // ---- final projection to output ----
  gemm(Zb, wo, d_out, BT, BDIM, BDIM, 0, nullptr);
}

// Round 3
// 823.607 us; speedup vs baseline: 2.4198x; 2.4198x over previous
//
#include <hip/hip_runtime.h>
#include <hip/hip_bf16.h>
#include <math.h>

#define BDIM 1024
#define TDIM 4096
#define BT   16384   // B*T
#define KEXPN 8
#define RRANK 64
#define KR   512     // KEXPN*RRANK
#define KRE  544     // extended K (512 + 8 bias cols + 24 zero pad)
#define NCH  64
#define TC   64      // T per chunk (NCH*TC == TDIM)

typedef __attribute__((ext_vector_type(8))) short bf16x8;
typedef __attribute__((ext_vector_type(4))) float f32x4;

typedef __attribute__((address_space(1))) char g_char;
typedef __attribute__((address_space(3))) char l_char;

// async 16B global->LDS: per-lane global addr, wave-uniform LDS base (+lane*16 by HW)
__device__ __forceinline__ void gload16(const short* g, short* lds_base_uniform) {
  __builtin_amdgcn_global_load_lds((const g_char*)(const char*)g,
                                   (l_char*)(char*)lds_base_uniform, 16, 0, 0);
}

// ---------------- elementwise conversion f32 -> bf16 (vectorized x4) ----------------
__global__ __launch_bounds__(256) void cvt_bf16_kernel(const float* __restrict__ in,
    __hip_bfloat16* __restrict__ out, long n4) {
  long id = (long)blockIdx.x * 256 + threadIdx.x;
  if (id >= n4) return;
  f32x4 v = ((const f32x4*)in)[id];
  long i = id * 4;
  out[i + 0] = __float2bfloat16(v[0]);
  out[i + 1] = __float2bfloat16(v[1]);
  out[i + 2] = __float2bfloat16(v[2]);
  out[i + 3] = __float2bfloat16(v[3]);
}

// ---------------- transpose-pack: out[e][d] = in[d][e], f32 -> bf16, D x D ----------------
__global__ __launch_bounds__(256) void transpose_pack_kernel(const float* __restrict__ in,
    __hip_bfloat16* __restrict__ out) {
  int id = blockIdx.x * 256 + threadIdx.x;   // 0 .. D*D
  if (id >= BDIM * BDIM) return;
  int d = id & (BDIM - 1);
  int e = id >> 10;
  out[(size_t)e * BDIM + d] = __float2bfloat16(in[(size_t)d * BDIM + e]);
}

// ---------------- pack V (K,D,R) -> Vmat[(k*64+r)][d] bf16 ----------------
__global__ __launch_bounds__(256) void pack_vmat_kernel(const float* __restrict__ V,
    __hip_bfloat16* __restrict__ out) {
  int id = blockIdx.x * 256 + threadIdx.x;     // 0 .. KR*BDIM
  if (id >= KR * BDIM) return;
  int d = id & (BDIM - 1);
  int kr = id >> 10;
  int k = kr >> 6, r = kr & 63;
  out[(size_t)kr * BDIM + d] = __float2bfloat16(V[((size_t)k * BDIM + d) * RRANK + r]);
}

// ---------------- pack U (K,D,R) + b (K,D) -> Ut[d][c] bf16, c in [0,544) ----------------
__global__ __launch_bounds__(256) void pack_ut_kernel(const float* __restrict__ U,
    const float* __restrict__ bvec, __hip_bfloat16* __restrict__ out) {
  int id = blockIdx.x * 256 + threadIdx.x;     // 0 .. BDIM*KRE
  if (id >= BDIM * KRE) return;
  int d = id / KRE;
  int c = id - d * KRE;
  float v;
  if (c < KR) {
    int k = c >> 6, r = c & 63;
    v = U[((size_t)k * BDIM + d) * RRANK + r];
  } else if (c < KR + KEXPN) {
    v = bvec[(size_t)(c - KR) * BDIM + d];
  } else {
    v = 0.0f;
  }
  out[(size_t)d * KRE + c] = __float2bfloat16(v);
}

// ---------------- m97-structure GEMM: C(MxN) = A(MxK) * B(NxK)^T, bf16 in, f32 acc ----------------
// 128x128 tile, BK=32, 4 waves (2x2), 4x4 16x16x32 fragments per wave, global_load_lds staging.
// EPI: 0 = store f32, 1 = store bf16, 2 = bias + exact GELU -> bf16, 3 = accumulate into f32 C
template<int EPI>
__global__ __launch_bounds__(256) void gemm_nt(const __hip_bfloat16* __restrict__ A,
    const __hip_bfloat16* __restrict__ B, void* __restrict__ Cv,
    const float* __restrict__ bias, int M, int N, int Kd) {
  __shared__ __align__(16) short Als[128 * 32];   // 8 KB, row-major [128][32]
  __shared__ __align__(16) short Bls[128 * 32];   // 8 KB
  const short* As = (const short*)A;
  const short* Bs = (const short*)B;
  const int t  = threadIdx.x;
  const int w  = t >> 6;
  const int l  = t & 63;
  const int lr = l & 15;
  const int lk = l >> 4;
  const int wr = w >> 1;          // wave row 0..1
  const int wc = w & 1;           // wave col 0..1
  const int row0 = blockIdx.y * 128;
  const int col0 = blockIdx.x * 128;

  // staging map: lane l of wave w covers row w*16 + (l>>2), k-bytes (l&3)*16 (elems (l&3)*8)
  const int srow = w * 16 + (l >> 2);
  const int scol = (l & 3) * 8;
  const short* ag0 = As + (size_t)(row0 + srow) * Kd + scol;
  const short* ag1 = As + (size_t)(row0 + 64 + srow) * Kd + scol;
  const short* bg0 = Bs + (size_t)(col0 + srow) * Kd + scol;
  const short* bg1 = Bs + (size_t)(col0 + 64 + srow) * Kd + scol;
  short* alds0 = Als + w * 512;            // byte offset w*1024
  short* alds1 = Als + 2048 + w * 512;     // +4096 B
  short* blds0 = Bls + w * 512;
  short* blds1 = Bls + 2048 + w * 512;

  f32x4 acc[4][4] = {};

  for (int k0 = 0; k0 < Kd; k0 += 32) {
    gload16(ag0 + k0, alds0);
    gload16(ag1 + k0, alds1);
    gload16(bg0 + k0, blds0);
    gload16(bg1 + k0, blds1);
    __syncthreads();               // compiler drains vmcnt before barrier

    bf16x8 af[4], bf[4];
    #pragma unroll
    for (int i = 0; i < 4; i++)
      af[i] = *(const bf16x8*)&Als[(wr * 64 + i * 16 + lr) * 32 + lk * 8];
    #pragma unroll
    for (int j = 0; j < 4; j++)
      bf[j] = *(const bf16x8*)&Bls[(wc * 64 + j * 16 + lr) * 32 + lk * 8];
    #pragma unroll
    for (int i = 0; i < 4; i++)
      #pragma unroll
      for (int j = 0; j < 4; j++)
        acc[i][j] = __builtin_amdgcn_mfma_f32_16x16x32_bf16(af[i], bf[j], acc[i][j], 0, 0, 0);
    __syncthreads();               // all waves done reading before next stage
  }

  #pragma unroll
  for (int i = 0; i < 4; i++)
    #pragma unroll
    for (int j = 0; j < 4; j++)
      #pragma unroll
      for (int g = 0; g < 4; g++) {
        int r = row0 + wr * 64 + i * 16 + lk * 4 + g;
        int c = col0 + wc * 64 + j * 16 + lr;
        size_t idx = (size_t)r * N + c;
        float v = acc[i][j][g];
        if (EPI == 0) {
          ((float*)Cv)[idx] = v;
        } else if (EPI == 1) {
          ((__hip_bfloat16*)Cv)[idx] = __float2bfloat16(v);
        } else if (EPI == 2) {
          float xv = v + bias[c];
          float gl = 0.5f * xv * (1.0f + erff(xv * 0.70710678118654752f));
          ((__hip_bfloat16*)Cv)[idx] = __float2bfloat16(gl);
        } else {
          ((float*)Cv)[idx] += v;
        }
      }
}

// ---------------- router: logits = H @ w2^T + b2 + ebias; softmax over 8 (H is bf16) ----------------
__global__ __launch_bounds__(256) void router_kernel(const __hip_bfloat16* __restrict__ H,
    const float* __restrict__ w2, const float* __restrict__ b2,
    const float* __restrict__ ebias, float* __restrict__ wgt) {
  int wv = threadIdx.x >> 6;
  int l  = threadIdx.x & 63;
  int row = blockIdx.x * 4 + wv;
  if (row >= BT) return;
  float acc[KEXPN] = {};
  for (int i = 0; i < BDIM / 64; i++) {
    int h = i * 64 + l;
    float hv = __bfloat162float(H[(size_t)row * BDIM + h]);
    #pragma unroll
    for (int k = 0; k < KEXPN; k++) acc[k] += hv * w2[k * BDIM + h];
  }
  #pragma unroll
  for (int k = 0; k < KEXPN; k++)
    for (int off = 32; off; off >>= 1) acc[k] += __shfl_down(acc[k], off);
  if (l == 0) {
    float lg[KEXPN];
    float mx = -1e30f;
    #pragma unroll
    for (int k = 0; k < KEXPN; k++) { lg[k] = acc[k] + b2[k] + ebias[k]; mx = fmaxf(mx, lg[k]); }
    float s = 0.0f;
    #pragma unroll
    for (int k = 0; k < KEXPN; k++) { lg[k] = expf(lg[k] - mx); s += lg[k]; }
    float inv = 1.0f / s;
    #pragma unroll
    for (int k = 0; k < KEXPN; k++) wgt[(size_t)row * KEXPN + k] = lg[k] * inv;
  }
}

// ---------------- cumsum phase 1: per-chunk sums ----------------
__global__ __launch_bounds__(512) void chunksum_kernel(const float* __restrict__ yW,
    float* __restrict__ S) {
  int kr = threadIdx.x;       // 0..511
  int ch = blockIdx.x;        // 0..63
  int b  = blockIdx.y;        // 0..3
  size_t base = ((size_t)b * TDIM + ch * TC) * KR + kr;
  float s = 0.0f;
  for (int t = 0; t < TC; t++) s += yW[base + (size_t)t * KR];
  S[((size_t)b * NCH + ch) * KR + kr] = s;
}

// ---------------- cumsum phase 2: exclusive scan of chunk sums (in place) ----------------
__global__ __launch_bounds__(512) void scan_chunks_kernel(float* __restrict__ S) {
  int kr = threadIdx.x;
  int b  = blockIdx.x;
  float run = 0.0f;
  for (int ch = 0; ch < NCH; ch++) {
    size_t i = ((size_t)b * NCH + ch) * KR + kr;
    float v = S[i];
    S[i] = run;
    run += v;
  }
}

// ---------------- cumsum phase 3 + combine: P = bf16(xV * cum(yW) * w * scale) ----------------
__global__ __launch_bounds__(512) void combine_kernel(const float* __restrict__ yW,
    const float* __restrict__ S, const float* __restrict__ xV,
    const float* __restrict__ wgt, const float* __restrict__ alphaPtr, int useAlpha,
    __hip_bfloat16* __restrict__ P) {
  int kr = threadIdx.x;
  int ch = blockIdx.x;
  int b  = blockIdx.y;
  int k  = kr >> 6;
  float scale = useAlpha ? alphaPtr[0] : 1.0f;
  float run = S[((size_t)b * NCH + ch) * KR + kr];
  for (int t0 = 0; t0 < TC; t0++) {
    size_t row = (size_t)b * TDIM + ch * TC + t0;
    run += yW[row * KR + kr];
    float p = xV[row * KR + kr] * run * wgt[row * KEXPN + k] * scale;
    P[row * KRE + kr] = __float2bfloat16(p);
  }
}

// ---------------- fill extension columns of P: weights (scaled) then zeros ----------------
__global__ __launch_bounds__(256) void extfill_kernel(__hip_bfloat16* __restrict__ P,
    const float* __restrict__ wgt, const float* __restrict__ alphaPtr, int useAlpha) {
  int id = blockIdx.x * 256 + threadIdx.x;   // BT*32
  int row = id >> 5, j = id & 31;
  if (row >= BT) return;
  float scale = useAlpha ? alphaPtr[0] : 1.0f;
  float v = (j < KEXPN) ? wgt[(size_t)row * KEXPN + j] * scale : 0.0f;
  P[(size_t)row * KRE + KR + j] = __float2bfloat16(v);
}

// ---------------- divide by n_valid and convert to bf16 ----------------
__global__ __launch_bounds__(256) void div_kernel(const float* __restrict__ F,
    __hip_bfloat16* __restrict__ Z) {
  long id = (long)blockIdx.x * 256 + threadIdx.x;   // BT*BDIM/4
  f32x4 v = ((const f32x4*)F)[id];
  long e = id * 4;
  int row = (int)(e >> 10);
  int t = row & (TDIM - 1);
  float s = 1.0f / (float)(t + 1);
  Z[e + 0] = __float2bfloat16(v[0] * s);
  Z[e + 1] = __float2bfloat16(v[1] * s);
  Z[e + 2] = __float2bfloat16(v[2] * s);
  Z[e + 3] = __float2bfloat16(v[3] * s);
}

// ---------------- sentinel: encode required workspace MB into d_out ----------------
__global__ __launch_bounds__(256) void fill_kernel(float* __restrict__ out, long n, float val) {
  long id = (long)blockIdx.x * 256 + threadIdx.x;
  if (id < n) out[id] = val;
}

extern "C" void kernel_launch(void* const* d_in, const int* in_sizes, int n_in,
                              void* d_out, int out_size, void* d_ws, size_t ws_size,
                              hipStream_t stream) {
  const float* x        = (const float*)d_in[0];
  const float* W_Q      = (const float*)d_in[1];
  const float* W_K      = (const float*)d_in[2];
  const float* W_O      = (const float*)d_in[3];
  const float* W_inv    = (const float*)d_in[4];
  const float* V_fwd    = (const float*)d_in[5];
  const float* W_fwd    = (const float*)d_in[6];
  const float* U_fwd    = (const float*)d_in[7];
  const float* b_fwd    = (const float*)d_in[8];
  const float* V_inv    = (const float*)d_in[9];
  const float* W_inv_e  = (const float*)d_in[10];
  const float* U_inv    = (const float*)d_in[11];
  const float* b_inv    = (const float*)d_in[12];
  const float* rw1      = (const float*)d_in[13];
  const float* rb1      = (const float*)d_in[14];
  const float* rw2      = (const float*)d_in[15];
  const float* rb2      = (const float*)d_in[16];
  const float* alphaPtr = (const float*)d_in[17];
  const float* ebias    = (const float*)d_in[18];

  char* ws = (char*)d_ws;
  size_t off = 0;
  auto alloc = [&](size_t sz) -> void* {
    void* p = ws + off;
    off += (sz + 255) & ~(size_t)255;
    return p;
  };

  // ---- small weight buffers (~25 MB) ----
  void* wq    = alloc((size_t)BDIM * BDIM * 2);
  void* wk    = alloc((size_t)BDIM * BDIM * 2);
  void* wo    = alloc((size_t)BDIM * BDIM * 2);
  void* w1    = alloc((size_t)BDIM * BDIM * 2);
  void* winvT = alloc((size_t)BDIM * BDIM * 2);   // W_inv transposed: [e][d] = W_inv[d][e]
  void* w1i   = alloc((size_t)BDIM * BDIM * 2);   // w1 @ W_inv
  void* vm_f  = alloc((size_t)KR * BDIM * 2);     // packed V_fwd
  void* wm_f  = alloc((size_t)KR * BDIM * 2);     // packed W_fwd
  void* vm_ie = alloc((size_t)KR * BDIM * 2);     // packed W_inv_exp
  void* vm_i  = alloc((size_t)KR * BDIM * 2);     // packed V_inv
  void* Gq    = alloc((size_t)KR * BDIM * 2);     // packed(W_inv_exp) @ W_inv  (xV_inv weights)
  void* Gk    = alloc((size_t)KR * BDIM * 2);     // packed(V_inv)     @ W_inv  (yW_inv weights)
  void* ut_f  = alloc((size_t)BDIM * KRE * 2);
  void* ut_i  = alloc((size_t)BDIM * KRE * 2);
  void* wgt_f = alloc((size_t)BT * KEXPN * 4);
  void* wgt_i = alloc((size_t)BT * KEXPN * 4);
  void* S     = alloc((size_t)4 * NCH * KR * 4);
  void* Pf    = alloc((size_t)BT * KRE * 2);
  void* Pi    = alloc((size_t)BT * KRE * 2);
  // ---- big slots (5 x 33.5 MB = 168 MB) ----
  void* s_Q   = alloc((size_t)BT * BDIM * 2);     // Q bf16; later (with s_K) F f32
  void* s_K   = alloc((size_t)BT * BDIM * 2);     // K bf16  (adjacent to s_Q)
  void* s_x   = alloc((size_t)BT * BDIM * 2);     // x bf16; later H bf16
  void* s_xV  = alloc((size_t)BT * KR * 4);       // xV f32;  later Zb bf16
  void* s_yW  = alloc((size_t)BT * KR * 4);       // yW f32
  void* F  = s_Q;   // 67.1 MB f32 spans s_Q+s_K (both dead by then, contiguous)
  void* H  = s_x;   // 33.5 MB bf16 after x is dead
  void* Zb = s_xV;  // 33.5 MB bf16 after xV is dead

  if (off > ws_size) {
    // Encode required MB into the output so the bench reports it as absmax.
    fill_kernel<<<dim3((unsigned)((out_size + 255) / 256)), 256, 0, stream>>>(
        (float*)d_out, (long)out_size, (float)(off >> 20));
    return;
  }

  auto cvt = [&](const float* in, void* out, long n) {
    long n4 = n / 4;
    cvt_bf16_kernel<<<dim3((unsigned)((n4 + 255) / 256)), dim3(256), 0, stream>>>(
        in, (__hip_bfloat16*)out, n4);
  };
  auto gemm = [&](const void* A, const void* Bm, void* C, int M, int N, int Kd,
                  int epi, const float* bias) {
    dim3 g(N / 128, M / 128);
    if (epi == 0)      gemm_nt<0><<<g, 256, 0, stream>>>((const __hip_bfloat16*)A, (const __hip_bfloat16*)Bm, C, bias, M, N, Kd);
    else if (epi == 1) gemm_nt<1><<<g, 256, 0, stream>>>((const __hip_bfloat16*)A, (const __hip_bfloat16*)Bm, C, bias, M, N, Kd);
    else if (epi == 2) gemm_nt<2><<<g, 256, 0, stream>>>((const __hip_bfloat16*)A, (const __hip_bfloat16*)Bm, C, bias, M, N, Kd);
    else               gemm_nt<3><<<g, 256, 0, stream>>>((const __hip_bfloat16*)A, (const __hip_bfloat16*)Bm, C, bias, M, N, Kd);
  };

  // ---- conversions & packing ----
  cvt(x,   s_x, (long)BT * BDIM);
  cvt(W_Q, wq,  (long)BDIM * BDIM);
  cvt(W_K, wk,  (long)BDIM * BDIM);
  cvt(W_O, wo,  (long)BDIM * BDIM);
  cvt(rw1, w1,  (long)BDIM * BDIM);
  {
    dim3 gt((BDIM * BDIM + 255) / 256);
    transpose_pack_kernel<<<gt, 256, 0, stream>>>(W_inv, (__hip_bfloat16*)winvT);
    dim3 g((KR * BDIM + 255) / 256);
    pack_vmat_kernel<<<g, 256, 0, stream>>>(V_fwd,   (__hip_bfloat16*)vm_f);
    pack_vmat_kernel<<<g, 256, 0, stream>>>(W_fwd,   (__hip_bfloat16*)wm_f);
    pack_vmat_kernel<<<g, 256, 0, stream>>>(W_inv_e, (__hip_bfloat16*)vm_ie);
    pack_vmat_kernel<<<g, 256, 0, stream>>>(V_inv,   (__hip_bfloat16*)vm_i);
    dim3 gu((BDIM * KRE + 255) / 256);
    pack_ut_kernel<<<gu, 256, 0, stream>>>(U_fwd, b_fwd, (__hip_bfloat16*)ut_f);
    pack_ut_kernel<<<gu, 256, 0, stream>>>(U_inv, b_inv, (__hip_bfloat16*)ut_i);
  }

  // ---- fold W_inv into inv-branch weights (tiny GEMMs) ----
  gemm(w1,    winvT, w1i, BDIM, BDIM, BDIM, 1, nullptr);
  gemm(vm_ie, winvT, Gq,  KR,   BDIM, BDIM, 1, nullptr);
  gemm(vm_i,  winvT, Gk,  KR,   BDIM, BDIM, 1, nullptr);

  // ---- projections ----
  gemm(s_x, wq, s_Q, BT, BDIM, BDIM, 1, nullptr);   // Q
  gemm(s_x, wk, s_K, BT, BDIM, BDIM, 1, nullptr);   // K   (x dead after this)

  dim3 gch(NCH, 4);

  // ---- forward branch ----
  gemm(s_Q, w1, H, BT, BDIM, BDIM, 2, rb1);         // H = gelu(Q w1^T + b1), bf16 (overlays x)
  router_kernel<<<dim3(BT / 4), 256, 0, stream>>>((const __hip_bfloat16*)H, rw2, rb2, ebias, (float*)wgt_f);
  gemm(s_Q, vm_f, s_xV, BT, KR, BDIM, 0, nullptr);  // xV = Q V_fwd
  gemm(s_K, wm_f, s_yW, BT, KR, BDIM, 0, nullptr);  // yW = K W_fwd
  chunksum_kernel<<<gch, 512, 0, stream>>>((const float*)s_yW, (float*)S);
  scan_chunks_kernel<<<dim3(4), 512, 0, stream>>>((float*)S);
  combine_kernel<<<gch, 512, 0, stream>>>((const float*)s_yW, (const float*)S,
      (const float*)s_xV, (const float*)wgt_f, alphaPtr, 0, (__hip_bfloat16*)Pf);
  extfill_kernel<<<dim3(BT * 32 / 256), 256, 0, stream>>>((__hip_bfloat16*)Pf,
      (const float*)wgt_f, alphaPtr, 0);

  // ---- inverse branch (reads Q,K with folded weights) ----
  gemm(s_Q, w1i, H, BT, BDIM, BDIM, 2, rb1);
  router_kernel<<<dim3(BT / 4), 256, 0, stream>>>((const __hip_bfloat16*)H, rw2, rb2, ebias, (float*)wgt_i);
  gemm(s_Q, Gq, s_xV, BT, KR, BDIM, 0, nullptr);    // xV_inv
  gemm(s_K, Gk, s_yW, BT, KR, BDIM, 0, nullptr);    // yW_inv   (Q,K dead after this)
  chunksum_kernel<<<gch, 512, 0, stream>>>((const float*)s_yW, (float*)S);
  scan_chunks_kernel<<<dim3(4), 512, 0, stream>>>((float*)S);
  combine_kernel<<<gch, 512, 0, stream>>>((const float*)s_yW, (const float*)S,
      (const float*)s_xV, (const float*)wgt_i, alphaPtr, 1, (__hip_bfloat16*)Pi);
  extfill_kernel<<<dim3(BT * 32 / 256), 256, 0, stream>>>((__hip_bfloat16*)Pi,
      (const float*)wgt_i, alphaPtr, 1);

  // ---- U projections (+bias via extended K), fwd + alpha*inv accumulated into F ----
  gemm(Pf, ut_f, F, BT, BDIM, KRE, 0, nullptr);     // F overlays s_Q+s_K (dead)
  gemm(Pi, ut_i, F, BT, BDIM, KRE, 3, nullptr);

  // ---- divide by n_valid, convert to bf16 ----
  div_kernel<<<dim3(BT * BDIM / 4 / 256), 256, 0, stream>>>((const float*)F, (__hip_bfloat16*)Zb);

  // ---- final projection to output ----
  gemm(Zb, wo, d_out, BT, BDIM, BDIM, 0, nullptr);
}

// Round 4
// 683.655 us; speedup vs baseline: 2.9152x; 1.2047x over previous
//
#include <hip/hip_runtime.h>
#include <hip/hip_bf16.h>
#include <math.h>

#define BDIM 1024
#define TDIM 4096
#define BT   16384   // B*T
#define KEXPN 8
#define RRANK 64
#define KR   512     // KEXPN*RRANK
#define KRE  544     // extended K (512 + 8 bias cols + 24 zero pad)
#define NCH  64
#define TC   64      // T per chunk (NCH*TC == TDIM)

typedef __attribute__((ext_vector_type(8))) short bf16x8;
typedef __attribute__((ext_vector_type(4))) float f32x4;

typedef __attribute__((address_space(1))) char g_char;
typedef __attribute__((address_space(3))) char l_char;

// async 16B global->LDS: per-lane global addr, wave-uniform LDS base (+lane*16 by HW)
__device__ __forceinline__ void gload16(const short* g, short* lds_base_uniform) {
  __builtin_amdgcn_global_load_lds((const g_char*)(const char*)g,
                                   (l_char*)(char*)lds_base_uniform, 16, 0, 0);
}

// ---------------- elementwise conversion f32 -> bf16 (vectorized x4) ----------------
__global__ __launch_bounds__(256) void cvt_bf16_kernel(const float* __restrict__ in,
    __hip_bfloat16* __restrict__ out, long n4) {
  long id = (long)blockIdx.x * 256 + threadIdx.x;
  if (id >= n4) return;
  f32x4 v = ((const f32x4*)in)[id];
  long i = id * 4;
  out[i + 0] = __float2bfloat16(v[0]);
  out[i + 1] = __float2bfloat16(v[1]);
  out[i + 2] = __float2bfloat16(v[2]);
  out[i + 3] = __float2bfloat16(v[3]);
}

// ---------------- transpose-pack: out[e][d] = in[d][e], f32 -> bf16, D x D ----------------
__global__ __launch_bounds__(256) void transpose_pack_kernel(const float* __restrict__ in,
    __hip_bfloat16* __restrict__ out) {
  int id = blockIdx.x * 256 + threadIdx.x;   // 0 .. D*D
  if (id >= BDIM * BDIM) return;
  int d = id & (BDIM - 1);
  int e = id >> 10;
  out[(size_t)e * BDIM + d] = __float2bfloat16(in[(size_t)d * BDIM + e]);
}

// ---------------- pack V (K,D,R) -> Vmat[(k*64+r)][d] bf16 ----------------
__global__ __launch_bounds__(256) void pack_vmat_kernel(const float* __restrict__ V,
    __hip_bfloat16* __restrict__ out) {
  int id = blockIdx.x * 256 + threadIdx.x;     // 0 .. KR*BDIM
  if (id >= KR * BDIM) return;
  int d = id & (BDIM - 1);
  int kr = id >> 10;
  int k = kr >> 6, r = kr & 63;
  out[(size_t)kr * BDIM + d] = __float2bfloat16(V[((size_t)k * BDIM + d) * RRANK + r]);
}

// ---------------- pack U (K,D,R) + b (K,D) -> Ut[d][c] bf16, c in [0,544) ----------------
__global__ __launch_bounds__(256) void pack_ut_kernel(const float* __restrict__ U,
    const float* __restrict__ bvec, __hip_bfloat16* __restrict__ out) {
  int id = blockIdx.x * 256 + threadIdx.x;     // 0 .. BDIM*KRE
  if (id >= BDIM * KRE) return;
  int d = id / KRE;
  int c = id - d * KRE;
  float v;
  if (c < KR) {
    int k = c >> 6, r = c & 63;
    v = U[((size_t)k * BDIM + d) * RRANK + r];
  } else if (c < KR + KEXPN) {
    v = bvec[(size_t)(c - KR) * BDIM + d];
  } else {
    v = 0.0f;
  }
  out[(size_t)d * KRE + c] = __float2bfloat16(v);
}

// ---------------- 2-phase m97-structure GEMM: C(MxN) = A(MxK) * B(NxK)^T ----------------
// 128x128 tile, BK=32 double-buffered, 4 waves (2x2), global_load_lds staging,
// STAGE(t+1) issued before compute(t), single barrier per K-step.
// Column-split epilogue: c < csplit -> Cv (stride csplit), else Cv2 (stride N-csplit).
// EPI: 0 = f32, 1 = bf16, 2 = bias + exact GELU -> bf16, 3 = accumulate f32
template<int EPI>
__global__ __launch_bounds__(256) void gemm_nt(const __hip_bfloat16* __restrict__ A,
    const __hip_bfloat16* __restrict__ B, void* __restrict__ Cv, void* __restrict__ Cv2,
    int csplit, const float* __restrict__ bias, int M, int N, int Kd) {
  __shared__ __align__(16) short Als[2][128 * 32];   // 2 x 8 KB
  __shared__ __align__(16) short Bls[2][128 * 32];

  // XCD-chunked swizzle (bijective when nwg % 8 == 0; all our grids are)
  int nbx = gridDim.x;
  int nwg = nbx * gridDim.y;
  int bx = blockIdx.x, by = blockIdx.y;
  if ((nwg & 7) == 0) {
    int orig = by * nbx + bx;
    int cpx = nwg >> 3;
    int id = (orig & 7) * cpx + (orig >> 3);
    bx = id % nbx; by = id / nbx;
  }

  const short* As = (const short*)A;
  const short* Bs = (const short*)B;
  const int t  = threadIdx.x;
  const int w  = t >> 6;
  const int l  = t & 63;
  const int lr = l & 15;
  const int lk = l >> 4;
  const int wr = w >> 1;          // wave row 0..1
  const int wc = w & 1;           // wave col 0..1
  const int row0 = by * 128;
  const int col0 = bx * 128;

  // staging map: lane l of wave w covers row w*16 + (l>>2), k-elems (l&3)*8
  const int srow = w * 16 + (l >> 2);
  const int scol = (l & 3) * 8;
  const short* ag0 = As + (size_t)(row0 + srow) * Kd + scol;
  const short* ag1 = As + (size_t)(row0 + 64 + srow) * Kd + scol;
  const short* bg0 = Bs + (size_t)(col0 + srow) * Kd + scol;
  const short* bg1 = Bs + (size_t)(col0 + 64 + srow) * Kd + scol;

  f32x4 acc[4][4] = {};
  const int nt = Kd / 32;

  auto stage = [&](int kt, int buf) {
    int k0 = kt * 32;
    gload16(ag0 + k0, &Als[buf][w * 512]);
    gload16(ag1 + k0, &Als[buf][2048 + w * 512]);
    gload16(bg0 + k0, &Bls[buf][w * 512]);
    gload16(bg1 + k0, &Bls[buf][2048 + w * 512]);
  };

  stage(0, 0);
  __syncthreads();                 // drain vmcnt: buf0 ready
  int cur = 0;
  for (int kt = 0; kt < nt; ++kt) {
    if (kt + 1 < nt) stage(kt + 1, cur ^ 1);   // async prefetch into other buffer
    bf16x8 af[4], bfr[4];
    #pragma unroll
    for (int i = 0; i < 4; i++)
      af[i] = *(const bf16x8*)&Als[cur][(wr * 64 + i * 16 + lr) * 32 + lk * 8];
    #pragma unroll
    for (int j = 0; j < 4; j++)
      bfr[j] = *(const bf16x8*)&Bls[cur][(wc * 64 + j * 16 + lr) * 32 + lk * 8];
    #pragma unroll
    for (int i = 0; i < 4; i++)
      #pragma unroll
      for (int j = 0; j < 4; j++)
        acc[i][j] = __builtin_amdgcn_mfma_f32_16x16x32_bf16(af[i], bfr[j], acc[i][j], 0, 0, 0);
    __syncthreads();               // drains my gloads (vmcnt0) + ds_reads; all waves synced
    cur ^= 1;
  }

  #pragma unroll
  for (int i = 0; i < 4; i++)
    #pragma unroll
    for (int j = 0; j < 4; j++)
      #pragma unroll
      for (int g = 0; g < 4; g++) {
        int r = row0 + wr * 64 + i * 16 + lk * 4 + g;
        int c = col0 + wc * 64 + j * 16 + lr;
        float v = acc[i][j][g];
        void* dst = Cv;
        int cc = c, stride = csplit;
        if (c >= csplit) { dst = Cv2; cc = c - csplit; stride = N - csplit; }
        size_t idx = (size_t)r * stride + cc;
        if (EPI == 0) {
          ((float*)dst)[idx] = v;
        } else if (EPI == 1) {
          ((__hip_bfloat16*)dst)[idx] = __float2bfloat16(v);
        } else if (EPI == 2) {
          float xv = v + bias[cc];
          float gl = 0.5f * xv * (1.0f + erff(xv * 0.70710678118654752f));
          ((__hip_bfloat16*)dst)[idx] = __float2bfloat16(gl);
        } else {
          ((float*)dst)[idx] += v;
        }
      }
}

// ---------------- router: logits = H @ w2^T + b2 + ebias; softmax over 8 (H is bf16) ----------------
__global__ __launch_bounds__(256) void router_kernel(const __hip_bfloat16* __restrict__ H,
    const float* __restrict__ w2, const float* __restrict__ b2,
    const float* __restrict__ ebias, float* __restrict__ wgt) {
  int wv = threadIdx.x >> 6;
  int l  = threadIdx.x & 63;
  int row = blockIdx.x * 4 + wv;
  if (row >= BT) return;
  float acc[KEXPN] = {};
  for (int i = 0; i < BDIM / 64; i++) {
    int h = i * 64 + l;
    float hv = __bfloat162float(H[(size_t)row * BDIM + h]);
    #pragma unroll
    for (int k = 0; k < KEXPN; k++) acc[k] += hv * w2[k * BDIM + h];
  }
  #pragma unroll
  for (int k = 0; k < KEXPN; k++)
    for (int off = 32; off; off >>= 1) acc[k] += __shfl_down(acc[k], off);
  if (l == 0) {
    float lg[KEXPN];
    float mx = -1e30f;
    #pragma unroll
    for (int k = 0; k < KEXPN; k++) { lg[k] = acc[k] + b2[k] + ebias[k]; mx = fmaxf(mx, lg[k]); }
    float s = 0.0f;
    #pragma unroll
    for (int k = 0; k < KEXPN; k++) { lg[k] = expf(lg[k] - mx); s += lg[k]; }
    float inv = 1.0f / s;
    #pragma unroll
    for (int k = 0; k < KEXPN; k++) wgt[(size_t)row * KEXPN + k] = lg[k] * inv;
  }
}

// ---------------- cumsum phase 1: per-chunk sums ----------------
__global__ __launch_bounds__(512) void chunksum_kernel(const float* __restrict__ yW,
    float* __restrict__ S) {
  int kr = threadIdx.x;       // 0..511
  int ch = blockIdx.x;        // 0..63
  int b  = blockIdx.y;        // 0..3
  size_t base = ((size_t)b * TDIM + ch * TC) * KR + kr;
  float s = 0.0f;
  for (int t = 0; t < TC; t++) s += yW[base + (size_t)t * KR];
  S[((size_t)b * NCH + ch) * KR + kr] = s;
}

// ---------------- cumsum phase 2: exclusive scan of chunk sums (in place) ----------------
__global__ __launch_bounds__(512) void scan_chunks_kernel(float* __restrict__ S) {
  int kr = threadIdx.x;
  int b  = blockIdx.x;
  float run = 0.0f;
  for (int ch = 0; ch < NCH; ch++) {
    size_t i = ((size_t)b * NCH + ch) * KR + kr;
    float v = S[i];
    S[i] = run;
    run += v;
  }
}

// ---------------- cumsum phase 3 + combine: P = bf16(xV * cum(yW) * w * scale) ----------------
__global__ __launch_bounds__(512) void combine_kernel(const float* __restrict__ yW,
    const float* __restrict__ S, const float* __restrict__ xV,
    const float* __restrict__ wgt, const float* __restrict__ alphaPtr, int useAlpha,
    __hip_bfloat16* __restrict__ P) {
  int kr = threadIdx.x;
  int ch = blockIdx.x;
  int b  = blockIdx.y;
  int k  = kr >> 6;
  float scale = useAlpha ? alphaPtr[0] : 1.0f;
  float run = S[((size_t)b * NCH + ch) * KR + kr];
  for (int t0 = 0; t0 < TC; t0++) {
    size_t row = (size_t)b * TDIM + ch * TC + t0;
    run += yW[row * KR + kr];
    float p = xV[row * KR + kr] * run * wgt[row * KEXPN + k] * scale;
    P[row * KRE + kr] = __float2bfloat16(p);
  }
}

// ---------------- fill extension columns of P: weights (scaled) then zeros ----------------
__global__ __launch_bounds__(256) void extfill_kernel(__hip_bfloat16* __restrict__ P,
    const float* __restrict__ wgt, const float* __restrict__ alphaPtr, int useAlpha) {
  int id = blockIdx.x * 256 + threadIdx.x;   // BT*32
  int row = id >> 5, j = id & 31;
  if (row >= BT) return;
  float scale = useAlpha ? alphaPtr[0] : 1.0f;
  float v = (j < KEXPN) ? wgt[(size_t)row * KEXPN + j] * scale : 0.0f;
  P[(size_t)row * KRE + KR + j] = __float2bfloat16(v);
}

// ---------------- divide by n_valid and convert to bf16 ----------------
__global__ __launch_bounds__(256) void div_kernel(const float* __restrict__ F,
    __hip_bfloat16* __restrict__ Z) {
  long id = (long)blockIdx.x * 256 + threadIdx.x;   // BT*BDIM/4
  f32x4 v = ((const f32x4*)F)[id];
  long e = id * 4;
  int row = (int)(e >> 10);
  int t = row & (TDIM - 1);
  float s = 1.0f / (float)(t + 1);
  Z[e + 0] = __float2bfloat16(v[0] * s);
  Z[e + 1] = __float2bfloat16(v[1] * s);
  Z[e + 2] = __float2bfloat16(v[2] * s);
  Z[e + 3] = __float2bfloat16(v[3] * s);
}

// ---------------- sentinel: encode required workspace MB into d_out ----------------
__global__ __launch_bounds__(256) void fill_kernel(float* __restrict__ out, long n, float val) {
  long id = (long)blockIdx.x * 256 + threadIdx.x;
  if (id < n) out[id] = val;
}

extern "C" void kernel_launch(void* const* d_in, const int* in_sizes, int n_in,
                              void* d_out, int out_size, void* d_ws, size_t ws_size,
                              hipStream_t stream) {
  const float* x        = (const float*)d_in[0];
  const float* W_Q      = (const float*)d_in[1];
  const float* W_K      = (const float*)d_in[2];
  const float* W_O      = (const float*)d_in[3];
  const float* W_inv    = (const float*)d_in[4];
  const float* V_fwd    = (const float*)d_in[5];
  const float* W_fwd    = (const float*)d_in[6];
  const float* U_fwd    = (const float*)d_in[7];
  const float* b_fwd    = (const float*)d_in[8];
  const float* V_inv    = (const float*)d_in[9];
  const float* W_inv_e  = (const float*)d_in[10];
  const float* U_inv    = (const float*)d_in[11];
  const float* b_inv    = (const float*)d_in[12];
  const float* rw1      = (const float*)d_in[13];
  const float* rb1      = (const float*)d_in[14];
  const float* rw2      = (const float*)d_in[15];
  const float* rb2      = (const float*)d_in[16];
  const float* alphaPtr = (const float*)d_in[17];
  const float* ebias    = (const float*)d_in[18];

  char* ws = (char*)d_ws;
  size_t off = 0;
  auto alloc = [&](size_t sz) -> void* {
    void* p = ws + off;
    off += (sz + 255) & ~(size_t)255;
    return p;
  };

  // ---- small weight buffers ----
  void* wqk   = alloc((size_t)2 * BDIM * BDIM * 2); // [W_Q rows | W_K rows], contiguous N=2048
  void* w1p   = alloc((size_t)2 * BDIM * BDIM * 2); // [w1 rows | w1i rows], contiguous N=2048
  void* wo    = alloc((size_t)BDIM * BDIM * 2);
  void* winvT = alloc((size_t)BDIM * BDIM * 2);     // W_inv transposed
  void* vm_f  = alloc((size_t)KR * BDIM * 2);       // packed V_fwd
  void* wm_f  = alloc((size_t)KR * BDIM * 2);       // packed W_fwd
  void* vm_ie = alloc((size_t)KR * BDIM * 2);       // packed W_inv_exp
  void* vm_i  = alloc((size_t)KR * BDIM * 2);       // packed V_inv
  void* Gq    = alloc((size_t)KR * BDIM * 2);       // packed(W_inv_exp) @ W_inv
  void* Gk    = alloc((size_t)KR * BDIM * 2);       // packed(V_inv)     @ W_inv
  void* ut_f  = alloc((size_t)BDIM * KRE * 2);
  void* ut_i  = alloc((size_t)BDIM * KRE * 2);
  void* wgt_f = alloc((size_t)BT * KEXPN * 4);
  void* wgt_i = alloc((size_t)BT * KEXPN * 4);
  void* S     = alloc((size_t)4 * NCH * KR * 4);
  void* Pf    = alloc((size_t)BT * KRE * 2);
  void* Pi    = alloc((size_t)BT * KRE * 2);
  // ---- big slots ----
  void* s_Q   = alloc((size_t)BT * BDIM * 2);     // Q bf16; later (with s_K) F f32
  void* s_K   = alloc((size_t)BT * BDIM * 2);     // K bf16 (adjacent to s_Q)
  void* s_x   = alloc((size_t)BT * BDIM * 2);     // x bf16; later H_fwd bf16
  void* s_xV  = alloc((size_t)BT * KR * 4);       // xV f32; later Zb bf16
  void* s_yW  = alloc((size_t)BT * KR * 4);       // H_inv bf16 (early), then yW f32
  void* F  = s_Q;   // 67.1 MB f32 spans s_Q+s_K (dead by then, contiguous)
  void* Hf = s_x;   // H_fwd overlays x
  void* Hi = s_yW;  // H_inv parks in yW slot (consumed by router before yW GEMM)
  void* Zb = s_xV;  // bf16 after xV is dead

  if (off > ws_size) {
    fill_kernel<<<dim3((unsigned)((out_size + 255) / 256)), 256, 0, stream>>>(
        (float*)d_out, (long)out_size, (float)(off >> 20));
    return;
  }

  __hip_bfloat16* wq = (__hip_bfloat16*)wqk;
  __hip_bfloat16* wk = wq + (size_t)BDIM * BDIM;
  __hip_bfloat16* w1  = (__hip_bfloat16*)w1p;
  __hip_bfloat16* w1i = w1 + (size_t)BDIM * BDIM;

  auto cvt = [&](const float* in, void* out, long n) {
    long n4 = n / 4;
    cvt_bf16_kernel<<<dim3((unsigned)((n4 + 255) / 256)), dim3(256), 0, stream>>>(
        in, (__hip_bfloat16*)out, n4);
  };
  // split GEMM: Cv gets cols [0,csplit) stride csplit, Cv2 gets [csplit,N) stride N-csplit
  auto gemm2 = [&](const void* A, const void* Bm, void* C, void* C2, int csplit,
                   int M, int N, int Kd, int epi, const float* bias) {
    dim3 g(N / 128, M / 128);
    if (epi == 0)      gemm_nt<0><<<g, 256, 0, stream>>>((const __hip_bfloat16*)A, (const __hip_bfloat16*)Bm, C, C2, csplit, bias, M, N, Kd);
    else if (epi == 1) gemm_nt<1><<<g, 256, 0, stream>>>((const __hip_bfloat16*)A, (const __hip_bfloat16*)Bm, C, C2, csplit, bias, M, N, Kd);
    else if (epi == 2) gemm_nt<2><<<g, 256, 0, stream>>>((const __hip_bfloat16*)A, (const __hip_bfloat16*)Bm, C, C2, csplit, bias, M, N, Kd);
    else               gemm_nt<3><<<g, 256, 0, stream>>>((const __hip_bfloat16*)A, (const __hip_bfloat16*)Bm, C, C2, csplit, bias, M, N, Kd);
  };
  auto gemm = [&](const void* A, const void* Bm, void* C, int M, int N, int Kd,
                  int epi, const float* bias) {
    gemm2(A, Bm, C, C, N, M, N, Kd, epi, bias);
  };

  // ---- conversions & packing ----
  cvt(x,   s_x, (long)BT * BDIM);
  cvt(W_Q, wq,  (long)BDIM * BDIM);
  cvt(W_K, wk,  (long)BDIM * BDIM);
  cvt(W_O, wo,  (long)BDIM * BDIM);
  cvt(rw1, w1,  (long)BDIM * BDIM);
  {
    dim3 gt((BDIM * BDIM + 255) / 256);
    transpose_pack_kernel<<<gt, 256, 0, stream>>>(W_inv, (__hip_bfloat16*)winvT);
    dim3 g((KR * BDIM + 255) / 256);
    pack_vmat_kernel<<<g, 256, 0, stream>>>(V_fwd,   (__hip_bfloat16*)vm_f);
    pack_vmat_kernel<<<g, 256, 0, stream>>>(W_fwd,   (__hip_bfloat16*)wm_f);
    pack_vmat_kernel<<<g, 256, 0, stream>>>(W_inv_e, (__hip_bfloat16*)vm_ie);
    pack_vmat_kernel<<<g, 256, 0, stream>>>(V_inv,   (__hip_bfloat16*)vm_i);
    dim3 gu((BDIM * KRE + 255) / 256);
    pack_ut_kernel<<<gu, 256, 0, stream>>>(U_fwd, b_fwd, (__hip_bfloat16*)ut_f);
    pack_ut_kernel<<<gu, 256, 0, stream>>>(U_inv, b_inv, (__hip_bfloat16*)ut_i);
  }

  // ---- fold W_inv into inv-branch weights (tiny GEMMs) ----
  gemm(w1,    winvT, w1i, BDIM, BDIM, BDIM, 1, nullptr);   // w1i adjacent to w1
  gemm(vm_ie, winvT, Gq,  KR,   BDIM, BDIM, 1, nullptr);
  gemm(vm_i,  winvT, Gk,  KR,   BDIM, BDIM, 1, nullptr);

  // ---- fused Q|K projection: [Q|K] = x @ [W_Q; W_K]^T ----
  gemm2(s_x, wqk, s_Q, s_K, BDIM, BT, 2 * BDIM, BDIM, 1, nullptr);  // x dead after

  // ---- fused H: [H_fwd|H_inv] = gelu(Q @ [w1; w1i]^T + b1) ----
  gemm2(s_Q, w1p, Hf, Hi, BDIM, BT, 2 * BDIM, BDIM, 2, rb1);
  router_kernel<<<dim3(BT / 4), 256, 0, stream>>>((const __hip_bfloat16*)Hf, rw2, rb2, ebias, (float*)wgt_f);
  router_kernel<<<dim3(BT / 4), 256, 0, stream>>>((const __hip_bfloat16*)Hi, rw2, rb2, ebias, (float*)wgt_i);

  dim3 gch(NCH, 4);

  // ---- forward branch ----
  gemm(s_Q, vm_f, s_xV, BT, KR, BDIM, 0, nullptr);  // xV = Q V_fwd
  gemm(s_K, wm_f, s_yW, BT, KR, BDIM, 0, nullptr);  // yW = K W_fwd (overwrites H_inv, consumed)
  chunksum_kernel<<<gch, 512, 0, stream>>>((const float*)s_yW, (float*)S);
  scan_chunks_kernel<<<dim3(4), 512, 0, stream>>>((float*)S);
  combine_kernel<<<gch, 512, 0, stream>>>((const float*)s_yW, (const float*)S,
      (const float*)s_xV, (const float*)wgt_f, alphaPtr, 0, (__hip_bfloat16*)Pf);
  extfill_kernel<<<dim3(BT * 32 / 256), 256, 0, stream>>>((__hip_bfloat16*)Pf,
      (const float*)wgt_f, alphaPtr, 0);

  // ---- inverse branch (reads Q,K with folded weights) ----
  gemm(s_Q, Gq, s_xV, BT, KR, BDIM, 0, nullptr);    // xV_inv
  gemm(s_K, Gk, s_yW, BT, KR, BDIM, 0, nullptr);    // yW_inv   (Q,K dead after this)
  chunksum_kernel<<<gch, 512, 0, stream>>>((const float*)s_yW, (float*)S);
  scan_chunks_kernel<<<dim3(4), 512, 0, stream>>>((float*)S);
  combine_kernel<<<gch, 512, 0, stream>>>((const float*)s_yW, (const float*)S,
      (const float*)s_xV, (const float*)wgt_i, alphaPtr, 1, (__hip_bfloat16*)Pi);
  extfill_kernel<<<dim3(BT * 32 / 256), 256, 0, stream>>>((__hip_bfloat16*)Pi,
      (const float*)wgt_i, alphaPtr, 1);

  // ---- U projections (+bias via extended K), fwd + alpha*inv accumulated into F ----
  gemm(Pf, ut_f, F, BT, BDIM, KRE, 0, nullptr);     // F overlays s_Q+s_K (dead)
  gemm(Pi, ut_i, F, BT, BDIM, KRE, 3, nullptr);

  // ---- divide by n_valid, convert to bf16 ----
  div_kernel<<<dim3(BT * BDIM / 4 / 256), 256, 0, stream>>>((const float*)F, (__hip_bfloat16*)Zb);

  // ---- final projection to output ----
  gemm(Zb, wo, d_out, BT, BDIM, BDIM, 0, nullptr);
}

// Round 5
// 617.299 us; speedup vs baseline: 3.2285x; 1.1075x over previous
//
#include <hip/hip_runtime.h>
#include <hip/hip_bf16.h>
#include <math.h>

#define BDIM 1024
#define TDIM 4096
#define BT   16384   // B*T
#define KEXPN 8
#define RRANK 64
#define KR   512     // KEXPN*RRANK
#define KC   640     // per-branch extended width: 512 prod + 8 bias + 120 pad (5*128)
#define PW   1280    // concatenated P width (2*KC)
#define KRC  1024    // concatenated xV/yW width
#define NCH  64
#define TC   64      // T per chunk (NCH*TC == TDIM)

typedef __attribute__((ext_vector_type(8))) short bf16x8;
typedef __attribute__((ext_vector_type(4))) float f32x4;

typedef __attribute__((address_space(1))) char g_char;
typedef __attribute__((address_space(3))) char l_char;

// async 16B global->LDS: per-lane global addr, wave-uniform LDS base (+lane*16 by HW)
__device__ __forceinline__ void gload16(const short* g, short* lds_base_uniform) {
  __builtin_amdgcn_global_load_lds((const g_char*)(const char*)g,
                                   (l_char*)(char*)lds_base_uniform, 16, 0, 0);
}

// ---------------- elementwise conversion f32 -> bf16 (vectorized x4) ----------------
__global__ __launch_bounds__(256) void cvt_bf16_kernel(const float* __restrict__ in,
    __hip_bfloat16* __restrict__ out, long n4) {
  long id = (long)blockIdx.x * 256 + threadIdx.x;
  if (id >= n4) return;
  f32x4 v = ((const f32x4*)in)[id];
  long i = id * 4;
  out[i + 0] = __float2bfloat16(v[0]);
  out[i + 1] = __float2bfloat16(v[1]);
  out[i + 2] = __float2bfloat16(v[2]);
  out[i + 3] = __float2bfloat16(v[3]);
}

// ---------------- transpose-pack: out[e][d] = in[d][e], f32 -> bf16, D x D ----------------
__global__ __launch_bounds__(256) void transpose_pack_kernel(const float* __restrict__ in,
    __hip_bfloat16* __restrict__ out) {
  int id = blockIdx.x * 256 + threadIdx.x;   // 0 .. D*D
  if (id >= BDIM * BDIM) return;
  int d = id & (BDIM - 1);
  int e = id >> 10;
  out[(size_t)e * BDIM + d] = __float2bfloat16(in[(size_t)d * BDIM + e]);
}

// ---------------- pack V (K,D,R) -> Vmat[(k*64+r)][d] bf16 ----------------
__global__ __launch_bounds__(256) void pack_vmat_kernel(const float* __restrict__ V,
    __hip_bfloat16* __restrict__ out) {
  int id = blockIdx.x * 256 + threadIdx.x;     // 0 .. KR*BDIM
  if (id >= KR * BDIM) return;
  int d = id & (BDIM - 1);
  int kr = id >> 10;
  int k = kr >> 6, r = kr & 63;
  out[(size_t)kr * BDIM + d] = __float2bfloat16(V[((size_t)k * BDIM + d) * RRANK + r]);
}

// ---------------- pack U (K,D,R)+b (K,D) -> utT[c][e], c in [0,640): 512 prod, 8 bias, 120 zero ----------------
__global__ __launch_bounds__(256) void pack_utT_kernel(const float* __restrict__ U,
    const float* __restrict__ bvec, __hip_bfloat16* __restrict__ out) {
  int id = blockIdx.x * 256 + threadIdx.x;     // 0 .. KC*BDIM
  if (id >= KC * BDIM) return;
  int e = id & (BDIM - 1);
  int c = id >> 10;
  float v = 0.0f;
  if (c < KR) {
    int k = c >> 6, r = c & 63;
    v = U[((size_t)k * BDIM + e) * RRANK + r];
  } else if (c < KR + KEXPN) {
    v = bvec[(size_t)(c - KR) * BDIM + e];
  }
  out[(size_t)c * BDIM + e] = __float2bfloat16(v);
}

// ---------------- 2-phase m97-structure GEMM: C(MxN) = A(MxK) * B(NxK)^T ----------------
// 128x128 tile, BK=32 double-buffered, 4 waves (2x2), global_load_lds staging,
// STAGE(t+1) issued before compute(t), single barrier per K-step. XCD-chunked swizzle.
// Column-split epilogue: c < csplit -> Cv (leading dim ldc), else Cv2 (ldc2).
// EPI: 0 = f32, 1 = bf16, 2 = bias + exact GELU -> bf16, 4 = scale 1/(t+1) -> f32
template<int EPI>
__global__ __launch_bounds__(256) void gemm_nt(const __hip_bfloat16* __restrict__ A,
    const __hip_bfloat16* __restrict__ B, void* __restrict__ Cv, void* __restrict__ Cv2,
    int csplit, int ldc, int ldc2, const float* __restrict__ bias, int M, int N, int Kd) {
  __shared__ __align__(16) short Als[2][128 * 32];   // 2 x 8 KB
  __shared__ __align__(16) short Bls[2][128 * 32];

  // XCD-chunked swizzle (bijective when nwg % 8 == 0; all our grids are)
  int nbx = gridDim.x;
  int nwg = nbx * gridDim.y;
  int bx = blockIdx.x, by = blockIdx.y;
  if ((nwg & 7) == 0) {
    int orig = by * nbx + bx;
    int cpx = nwg >> 3;
    int id = (orig & 7) * cpx + (orig >> 3);
    bx = id % nbx; by = id / nbx;
  }

  const short* As = (const short*)A;
  const short* Bs = (const short*)B;
  const int t  = threadIdx.x;
  const int w  = t >> 6;
  const int l  = t & 63;
  const int lr = l & 15;
  const int lk = l >> 4;
  const int wr = w >> 1;          // wave row 0..1
  const int wc = w & 1;           // wave col 0..1
  const int row0 = by * 128;
  const int col0 = bx * 128;

  // staging map: lane l of wave w covers row w*16 + (l>>2), k-elems (l&3)*8
  const int srow = w * 16 + (l >> 2);
  const int scol = (l & 3) * 8;
  const short* ag0 = As + (size_t)(row0 + srow) * Kd + scol;
  const short* ag1 = As + (size_t)(row0 + 64 + srow) * Kd + scol;
  const short* bg0 = Bs + (size_t)(col0 + srow) * Kd + scol;
  const short* bg1 = Bs + (size_t)(col0 + 64 + srow) * Kd + scol;

  f32x4 acc[4][4] = {};
  const int nt = Kd / 32;

  auto stage = [&](int kt, int buf) {
    int k0 = kt * 32;
    gload16(ag0 + k0, &Als[buf][w * 512]);
    gload16(ag1 + k0, &Als[buf][2048 + w * 512]);
    gload16(bg0 + k0, &Bls[buf][w * 512]);
    gload16(bg1 + k0, &Bls[buf][2048 + w * 512]);
  };

  stage(0, 0);
  __syncthreads();                 // drain vmcnt: buf0 ready
  int cur = 0;
  for (int kt = 0; kt < nt; ++kt) {
    if (kt + 1 < nt) stage(kt + 1, cur ^ 1);   // async prefetch into other buffer
    bf16x8 af[4], bfr[4];
    #pragma unroll
    for (int i = 0; i < 4; i++)
      af[i] = *(const bf16x8*)&Als[cur][(wr * 64 + i * 16 + lr) * 32 + lk * 8];
    #pragma unroll
    for (int j = 0; j < 4; j++)
      bfr[j] = *(const bf16x8*)&Bls[cur][(wc * 64 + j * 16 + lr) * 32 + lk * 8];
    #pragma unroll
    for (int i = 0; i < 4; i++)
      #pragma unroll
      for (int j = 0; j < 4; j++)
        acc[i][j] = __builtin_amdgcn_mfma_f32_16x16x32_bf16(af[i], bfr[j], acc[i][j], 0, 0, 0);
    __syncthreads();               // drains my gloads (vmcnt0) + ds_reads; all waves synced
    cur ^= 1;
  }

  #pragma unroll
  for (int i = 0; i < 4; i++)
    #pragma unroll
    for (int j = 0; j < 4; j++)
      #pragma unroll
      for (int g = 0; g < 4; g++) {
        int r = row0 + wr * 64 + i * 16 + lk * 4 + g;
        int c = col0 + wc * 64 + j * 16 + lr;
        float v = acc[i][j][g];
        void* dst = Cv;
        int cc = c, ld = ldc;
        if (c >= csplit) { dst = Cv2; cc = c - csplit; ld = ldc2; }
        size_t idx = (size_t)r * ld + cc;
        if (EPI == 0) {
          ((float*)dst)[idx] = v;
        } else if (EPI == 1) {
          ((__hip_bfloat16*)dst)[idx] = __float2bfloat16(v);
        } else if (EPI == 2) {
          float xv = v + bias[cc];
          float gl = 0.5f * xv * (1.0f + erff(xv * 0.70710678118654752f));
          ((__hip_bfloat16*)dst)[idx] = __float2bfloat16(gl);
        } else {  // EPI == 4: divide by n_valid, f32 out
          float s = 1.0f / (float)((r & (TDIM - 1)) + 1);
          ((float*)dst)[idx] = v * s;
        }
      }
}

// ---------------- router: logits = H @ w2^T + b2 + ebias; softmax over 8 (H is bf16) ----------------
__global__ __launch_bounds__(256) void router_kernel(const __hip_bfloat16* __restrict__ H,
    const float* __restrict__ w2, const float* __restrict__ b2,
    const float* __restrict__ ebias, float* __restrict__ wgt) {
  int wv = threadIdx.x >> 6;
  int l  = threadIdx.x & 63;
  int row = blockIdx.x * 4 + wv;
  if (row >= BT) return;
  float acc[KEXPN] = {};
  for (int i = 0; i < BDIM / 64; i++) {
    int h = i * 64 + l;
    float hv = __bfloat162float(H[(size_t)row * BDIM + h]);
    #pragma unroll
    for (int k = 0; k < KEXPN; k++) acc[k] += hv * w2[k * BDIM + h];
  }
  #pragma unroll
  for (int k = 0; k < KEXPN; k++)
    for (int off = 32; off; off >>= 1) acc[k] += __shfl_down(acc[k], off);
  if (l == 0) {
    float lg[KEXPN];
    float mx = -1e30f;
    #pragma unroll
    for (int k = 0; k < KEXPN; k++) { lg[k] = acc[k] + b2[k] + ebias[k]; mx = fmaxf(mx, lg[k]); }
    float s = 0.0f;
    #pragma unroll
    for (int k = 0; k < KEXPN; k++) { lg[k] = expf(lg[k] - mx); s += lg[k]; }
    float inv = 1.0f / s;
    #pragma unroll
    for (int k = 0; k < KEXPN; k++) wgt[(size_t)row * KEXPN + k] = lg[k] * inv;
  }
}

// ---------------- cumsum phase 1: per-chunk sums (width 1024) ----------------
__global__ __launch_bounds__(1024) void chunksum_kernel(const float* __restrict__ yW,
    float* __restrict__ S) {
  int j  = threadIdx.x;       // 0..1023
  int ch = blockIdx.x;        // 0..63
  int b  = blockIdx.y;        // 0..3
  size_t base = ((size_t)b * TDIM + ch * TC) * KRC + j;
  float s = 0.0f;
  for (int t = 0; t < TC; t++) s += yW[base + (size_t)t * KRC];
  S[((size_t)b * NCH + ch) * KRC + j] = s;
}

// ---------------- cumsum phase 2: exclusive scan of chunk sums (in place) ----------------
__global__ __launch_bounds__(1024) void scan_chunks_kernel(float* __restrict__ S) {
  int j = threadIdx.x;
  int b = blockIdx.x;
  float run = 0.0f;
  for (int ch = 0; ch < NCH; ch++) {
    size_t i = ((size_t)b * NCH + ch) * KRC + j;
    float v = S[i];
    S[i] = run;
    run += v;
  }
}

// ---------------- cumsum phase 3 + combine both branches -> Pcat ----------------
// col j<512: fwd (wgt_f, scale 1, P col j); j>=512: inv (wgt_i, scale alpha, P col j+128)
__global__ __launch_bounds__(1024) void combine_kernel(const float* __restrict__ yW,
    const float* __restrict__ S, const __hip_bfloat16* __restrict__ xV,
    const float* __restrict__ wf, const float* __restrict__ wi,
    const float* __restrict__ alphaPtr, __hip_bfloat16* __restrict__ P) {
  int j  = threadIdx.x;       // 0..1023
  int ch = blockIdx.x;
  int b  = blockIdx.y;
  float alpha = alphaPtr[0];
  float scale = (j < KR) ? 1.0f : alpha;
  const float* wgt = (j < KR) ? wf : wi;
  int k = (j & (KR - 1)) >> 6;
  int pcol = (j < KR) ? j : j + 128;
  float run = S[((size_t)b * NCH + ch) * KRC + j];
  for (int t0 = 0; t0 < TC; t0++) {
    size_t row = (size_t)b * TDIM + ch * TC + t0;
    run += yW[row * KRC + j];
    float p = __bfloat162float(xV[row * KRC + j]) * run * wgt[row * KEXPN + k] * scale;
    P[row * PW + pcol] = __float2bfloat16(p);
  }
}

// ---------------- fill extension columns of Pcat: router weights + zero pads ----------------
__global__ __launch_bounds__(256) void extfill_kernel(__hip_bfloat16* __restrict__ P,
    const float* __restrict__ wf, const float* __restrict__ wi,
    const float* __restrict__ alphaPtr) {
  int id = blockIdx.x * 256 + threadIdx.x;   // BT*256
  int row = id >> 8, j = id & 255;
  if (row >= BT) return;
  float alpha = alphaPtr[0];
  int half = j >> 7;            // 0 = fwd ext cols [512,640), 1 = inv ext cols [1152,1280)
  int jj = j & 127;
  int col = half ? (KC + KR + jj) : (KR + jj);
  const float* wgt = half ? wi : wf;
  float sc = half ? alpha : 1.0f;
  float v = (jj < KEXPN) ? wgt[(size_t)row * KEXPN + jj] * sc : 0.0f;
  P[(size_t)row * PW + col] = __float2bfloat16(v);
}

// ---------------- sentinel: encode required workspace MB into d_out ----------------
__global__ __launch_bounds__(256) void fill_kernel(float* __restrict__ out, long n, float val) {
  long id = (long)blockIdx.x * 256 + threadIdx.x;
  if (id < n) out[id] = val;
}

extern "C" void kernel_launch(void* const* d_in, const int* in_sizes, int n_in,
                              void* d_out, int out_size, void* d_ws, size_t ws_size,
                              hipStream_t stream) {
  const float* x        = (const float*)d_in[0];
  const float* W_Q      = (const float*)d_in[1];
  const float* W_K      = (const float*)d_in[2];
  const float* W_O      = (const float*)d_in[3];
  const float* W_inv    = (const float*)d_in[4];
  const float* V_fwd    = (const float*)d_in[5];
  const float* W_fwd    = (const float*)d_in[6];
  const float* U_fwd    = (const float*)d_in[7];
  const float* b_fwd    = (const float*)d_in[8];
  const float* V_inv    = (const float*)d_in[9];
  const float* W_inv_e  = (const float*)d_in[10];
  const float* U_inv    = (const float*)d_in[11];
  const float* b_inv    = (const float*)d_in[12];
  const float* rw1      = (const float*)d_in[13];
  const float* rb1      = (const float*)d_in[14];
  const float* rw2      = (const float*)d_in[15];
  const float* rb2      = (const float*)d_in[16];
  const float* alphaPtr = (const float*)d_in[17];
  const float* ebias    = (const float*)d_in[18];

  char* ws = (char*)d_ws;
  size_t off = 0;
  auto alloc = [&](size_t sz) -> void* {
    void* p = ws + off;
    off += (sz + 255) & ~(size_t)255;
    return p;
  };

  // ---- small weight buffers (~25 MB) ----
  void* wqk   = alloc((size_t)2 * BDIM * BDIM * 2); // [W_Q rows | W_K rows]
  void* w1p   = alloc((size_t)2 * BDIM * BDIM * 2); // [w1 rows | w1i rows]
  void* wo    = alloc((size_t)BDIM * BDIM * 2);
  void* winvT = alloc((size_t)BDIM * BDIM * 2);     // W_inv transposed
  void* vmq   = alloc((size_t)KRC * BDIM * 2);      // rows 0-511 vm_f, 512-1023 Gq
  void* wmG   = alloc((size_t)KRC * BDIM * 2);      // rows 0-511 wm_f, 512-1023 Gk
  void* vm_ie = alloc((size_t)KR * BDIM * 2);       // packed W_inv_exp (fold input)
  void* vm_i  = alloc((size_t)KR * BDIM * 2);       // packed V_inv (fold input)
  void* utTf  = alloc((size_t)KC * BDIM * 2);       // Ut_fwd^T  [c][e], 640x1024
  void* utTi  = alloc((size_t)KC * BDIM * 2);       // Ut_inv^T
  void* Mcat  = alloc((size_t)BDIM * PW * 2);       // [d][c]: cols 0-639 WO@Utf, 640-1279 WO@Uti
  void* wgt_f = alloc((size_t)BT * KEXPN * 4);
  void* wgt_i = alloc((size_t)BT * KEXPN * 4);
  void* S     = alloc((size_t)4 * NCH * KRC * 4);
  // ---- big slots ----
  void* s_Q   = alloc((size_t)BT * BDIM * 2);     // Q bf16; later Pcat spans s_Q+s_K
  void* s_K   = alloc((size_t)BT * BDIM * 2);     // K bf16 (adjacent)
  void* s_x   = alloc((size_t)BT * BDIM * 2);     // x bf16 -> Hf bf16 -> xVcat bf16
  void* s_yW  = alloc((size_t)BT * KRC * 4);      // Hi bf16 (early) -> yWcat f32
  void* Hf    = s_x;
  void* Hi    = s_yW;
  void* xVcat = s_x;    // after routers consume Hf
  void* Pcat  = s_Q;    // 41.9 MB bf16 spans s_Q+s_K (dead by then, contiguous)

  if (off > ws_size) {
    fill_kernel<<<dim3((unsigned)((out_size + 255) / 256)), 256, 0, stream>>>(
        (float*)d_out, (long)out_size, (float)(off >> 20));
    return;
  }

  __hip_bfloat16* wq  = (__hip_bfloat16*)wqk;
  __hip_bfloat16* wk  = wq + (size_t)BDIM * BDIM;
  __hip_bfloat16* w1  = (__hip_bfloat16*)w1p;
  __hip_bfloat16* w1i = w1 + (size_t)BDIM * BDIM;
  __hip_bfloat16* Gq  = (__hip_bfloat16*)vmq + (size_t)KR * BDIM;
  __hip_bfloat16* Gk  = (__hip_bfloat16*)wmG + (size_t)KR * BDIM;

  auto cvt = [&](const float* in, void* out, long n) {
    long n4 = n / 4;
    cvt_bf16_kernel<<<dim3((unsigned)((n4 + 255) / 256)), dim3(256), 0, stream>>>(
        in, (__hip_bfloat16*)out, n4);
  };
  // split GEMM: Cv gets cols [0,csplit) lead dim ldc, Cv2 gets [csplit,N) lead dim ldc2
  auto gemm2 = [&](const void* A, const void* Bm, void* C, void* C2, int csplit,
                   int ldc, int ldc2, int M, int N, int Kd, int epi, const float* bias) {
    dim3 g(N / 128, M / 128);
    if (epi == 0)      gemm_nt<0><<<g, 256, 0, stream>>>((const __hip_bfloat16*)A, (const __hip_bfloat16*)Bm, C, C2, csplit, ldc, ldc2, bias, M, N, Kd);
    else if (epi == 1) gemm_nt<1><<<g, 256, 0, stream>>>((const __hip_bfloat16*)A, (const __hip_bfloat16*)Bm, C, C2, csplit, ldc, ldc2, bias, M, N, Kd);
    else if (epi == 2) gemm_nt<2><<<g, 256, 0, stream>>>((const __hip_bfloat16*)A, (const __hip_bfloat16*)Bm, C, C2, csplit, ldc, ldc2, bias, M, N, Kd);
    else               gemm_nt<4><<<g, 256, 0, stream>>>((const __hip_bfloat16*)A, (const __hip_bfloat16*)Bm, C, C2, csplit, ldc, ldc2, bias, M, N, Kd);
  };
  auto gemm = [&](const void* A, const void* Bm, void* C, int M, int N, int Kd,
                  int epi, const float* bias) {
    gemm2(A, Bm, C, C, N, N, N, M, N, Kd, epi, bias);
  };

  // ---- conversions & packing ----
  cvt(x,   s_x, (long)BT * BDIM);
  cvt(W_Q, wq,  (long)BDIM * BDIM);
  cvt(W_K, wk,  (long)BDIM * BDIM);
  cvt(W_O, wo,  (long)BDIM * BDIM);
  cvt(rw1, w1,  (long)BDIM * BDIM);
  {
    dim3 gt((BDIM * BDIM + 255) / 256);
    transpose_pack_kernel<<<gt, 256, 0, stream>>>(W_inv, (__hip_bfloat16*)winvT);
    dim3 g((KR * BDIM + 255) / 256);
    pack_vmat_kernel<<<g, 256, 0, stream>>>(V_fwd,   (__hip_bfloat16*)vmq);   // rows 0-511
    pack_vmat_kernel<<<g, 256, 0, stream>>>(W_fwd,   (__hip_bfloat16*)wmG);   // rows 0-511
    pack_vmat_kernel<<<g, 256, 0, stream>>>(W_inv_e, (__hip_bfloat16*)vm_ie);
    pack_vmat_kernel<<<g, 256, 0, stream>>>(V_inv,   (__hip_bfloat16*)vm_i);
    dim3 gu((KC * BDIM + 255) / 256);
    pack_utT_kernel<<<gu, 256, 0, stream>>>(U_fwd, b_fwd, (__hip_bfloat16*)utTf);
    pack_utT_kernel<<<gu, 256, 0, stream>>>(U_inv, b_inv, (__hip_bfloat16*)utTi);
  }

  // ---- weight folds (tiny GEMMs) ----
  gemm(w1,    winvT, w1i, BDIM, BDIM, BDIM, 1, nullptr);   // w1i = w1 @ W_inv
  gemm(vm_ie, winvT, Gq,  KR,   BDIM, BDIM, 1, nullptr);   // Gq  = pack(W_inv_exp) @ W_inv
  gemm(vm_i,  winvT, Gk,  KR,   BDIM, BDIM, 1, nullptr);   // Gk  = pack(V_inv) @ W_inv
  // Mcat[d][c] = (W_O @ Ut)[d][c], written with leading dim PW into the two column halves
  gemm2(wo, utTf, Mcat, Mcat, KC, PW, PW, BDIM, KC, BDIM, 1, nullptr);
  gemm2(wo, utTi, (__hip_bfloat16*)Mcat + KC, (__hip_bfloat16*)Mcat + KC,
        KC, PW, PW, BDIM, KC, BDIM, 1, nullptr);

  // ---- fused Q|K projection: [Q|K] = x @ [W_Q; W_K]^T ----
  gemm2(s_x, wqk, s_Q, s_K, BDIM, BDIM, BDIM, BT, 2 * BDIM, BDIM, 1, nullptr);

  // ---- fused H: [H_fwd|H_inv] = gelu(Q @ [w1; w1i]^T + b1) ----
  gemm2(s_Q, w1p, Hf, Hi, BDIM, BDIM, BDIM, BT, 2 * BDIM, BDIM, 2, rb1);
  router_kernel<<<dim3(BT / 4), 256, 0, stream>>>((const __hip_bfloat16*)Hf, rw2, rb2, ebias, (float*)wgt_f);
  router_kernel<<<dim3(BT / 4), 256, 0, stream>>>((const __hip_bfloat16*)Hi, rw2, rb2, ebias, (float*)wgt_i);

  // ---- fused branch GEMMs: xVcat = Q @ [vm_f;Gq]^T (bf16, overlays Hf), yWcat = K @ [wm_f;Gk]^T (f32) ----
  gemm(s_Q, vmq, xVcat, BT, KRC, BDIM, 1, nullptr);
  gemm(s_K, wmG, s_yW,  BT, KRC, BDIM, 0, nullptr);   // Q,K dead after these two

  // ---- causal cumsum + combine both branches into Pcat (overlays Q+K) ----
  dim3 gch(NCH, 4);
  chunksum_kernel<<<gch, 1024, 0, stream>>>((const float*)s_yW, (float*)S);
  scan_chunks_kernel<<<dim3(4), 1024, 0, stream>>>((float*)S);
  combine_kernel<<<gch, 1024, 0, stream>>>((const float*)s_yW, (const float*)S,
      (const __hip_bfloat16*)xVcat, (const float*)wgt_f, (const float*)wgt_i,
      alphaPtr, (__hip_bfloat16*)Pcat);
  extfill_kernel<<<dim3(BT * 256 / 256), 256, 0, stream>>>((__hip_bfloat16*)Pcat,
      (const float*)wgt_f, (const float*)wgt_i, alphaPtr);

  // ---- single output GEMM: out = diag(1/n) * Pcat @ Mcat^T  (f32 to d_out) ----
  gemm(Pcat, Mcat, d_out, BT, BDIM, PW, 4, nullptr);
}

// Round 6
// 580.149 us; speedup vs baseline: 3.4353x; 1.0640x over previous
//
#include <hip/hip_runtime.h>
#include <hip/hip_bf16.h>
#include <math.h>

#define BDIM 1024
#define TDIM 4096
#define BT   16384   // B*T
#define KEXPN 8
#define RRANK 64
#define KR   512     // KEXPN*RRANK
#define KC   640     // per-branch extended width: 512 prod + 8 bias + 120 pad (5*128)
#define PW   1280    // concatenated P width (2*KC)
#define KRC  1024    // concatenated xV/yW width
#define NCH  64
#define TC   64      // T per chunk (NCH*TC == TDIM)

typedef __attribute__((ext_vector_type(8))) short bf16x8;
typedef __attribute__((ext_vector_type(4))) float f32x4;

typedef __attribute__((address_space(1))) char g_char;
typedef __attribute__((address_space(3))) char l_char;

// async 16B global->LDS: per-lane global addr, wave-uniform LDS base (+lane*16 by HW)
__device__ __forceinline__ void gload16(const short* g, short* lds_base_uniform) {
  __builtin_amdgcn_global_load_lds((const g_char*)(const char*)g,
                                   (l_char*)(char*)lds_base_uniform, 16, 0, 0);
}

// ---------------- elementwise conversion f32 -> bf16 (vectorized x4) ----------------
__global__ __launch_bounds__(256) void cvt_bf16_kernel(const float* __restrict__ in,
    __hip_bfloat16* __restrict__ out, long n4) {
  long id = (long)blockIdx.x * 256 + threadIdx.x;
  if (id >= n4) return;
  f32x4 v = ((const f32x4*)in)[id];
  long i = id * 4;
  out[i + 0] = __float2bfloat16(v[0]);
  out[i + 1] = __float2bfloat16(v[1]);
  out[i + 2] = __float2bfloat16(v[2]);
  out[i + 3] = __float2bfloat16(v[3]);
}

// ---------------- transpose-pack: out[e][d] = in[d][e], f32 -> bf16, D x D ----------------
__global__ __launch_bounds__(256) void transpose_pack_kernel(const float* __restrict__ in,
    __hip_bfloat16* __restrict__ out) {
  int id = blockIdx.x * 256 + threadIdx.x;   // 0 .. D*D
  if (id >= BDIM * BDIM) return;
  int d = id & (BDIM - 1);
  int e = id >> 10;
  out[(size_t)e * BDIM + d] = __float2bfloat16(in[(size_t)d * BDIM + e]);
}

// ---------------- pack V (K,D,R) -> Vmat[(k*64+r)][d] bf16 ----------------
__global__ __launch_bounds__(256) void pack_vmat_kernel(const float* __restrict__ V,
    __hip_bfloat16* __restrict__ out) {
  int id = blockIdx.x * 256 + threadIdx.x;     // 0 .. KR*BDIM
  if (id >= KR * BDIM) return;
  int d = id & (BDIM - 1);
  int kr = id >> 10;
  int k = kr >> 6, r = kr & 63;
  out[(size_t)kr * BDIM + d] = __float2bfloat16(V[((size_t)k * BDIM + d) * RRANK + r]);
}

// ---------------- pack U (K,D,R)+b (K,D) -> utT[c][e], c in [0,640) ----------------
__global__ __launch_bounds__(256) void pack_utT_kernel(const float* __restrict__ U,
    const float* __restrict__ bvec, __hip_bfloat16* __restrict__ out) {
  int id = blockIdx.x * 256 + threadIdx.x;     // 0 .. KC*BDIM
  if (id >= KC * BDIM) return;
  int e = id & (BDIM - 1);
  int c = id >> 10;
  float v = 0.0f;
  if (c < KR) {
    int k = c >> 6, r = c & 63;
    v = U[((size_t)k * BDIM + e) * RRANK + r];
  } else if (c < KR + KEXPN) {
    v = bvec[(size_t)(c - KR) * BDIM + e];
  }
  out[(size_t)c * BDIM + e] = __float2bfloat16(v);
}

// ================= 128^2 2-phase engine (small folds only) =================
template<int EPI>
__global__ __launch_bounds__(256) void gemm_nt(const __hip_bfloat16* __restrict__ A,
    const __hip_bfloat16* __restrict__ B, void* __restrict__ Cv, void* __restrict__ Cv2,
    int csplit, int ldc, int ldc2, const float* __restrict__ bias, int M, int N, int Kd) {
  __shared__ __align__(16) short Als[2][128 * 32];
  __shared__ __align__(16) short Bls[2][128 * 32];
  int nbx = gridDim.x;
  int nwg = nbx * gridDim.y;
  int bx = blockIdx.x, by = blockIdx.y;
  if ((nwg & 7) == 0) {
    int orig = by * nbx + bx;
    int cpx = nwg >> 3;
    int id = (orig & 7) * cpx + (orig >> 3);
    bx = id % nbx; by = id / nbx;
  }
  const short* As = (const short*)A;
  const short* Bs = (const short*)B;
  const int t  = threadIdx.x;
  const int w  = t >> 6;
  const int l  = t & 63;
  const int lr = l & 15;
  const int lk = l >> 4;
  const int wr = w >> 1;
  const int wc = w & 1;
  const int row0 = by * 128;
  const int col0 = bx * 128;
  const int srow = w * 16 + (l >> 2);
  const int scol = (l & 3) * 8;
  const short* ag0 = As + (size_t)(row0 + srow) * Kd + scol;
  const short* ag1 = As + (size_t)(row0 + 64 + srow) * Kd + scol;
  const short* bg0 = Bs + (size_t)(col0 + srow) * Kd + scol;
  const short* bg1 = Bs + (size_t)(col0 + 64 + srow) * Kd + scol;
  f32x4 acc[4][4] = {};
  const int nt = Kd / 32;
  auto stage = [&](int kt, int buf) {
    int k0 = kt * 32;
    gload16(ag0 + k0, &Als[buf][w * 512]);
    gload16(ag1 + k0, &Als[buf][2048 + w * 512]);
    gload16(bg0 + k0, &Bls[buf][w * 512]);
    gload16(bg1 + k0, &Bls[buf][2048 + w * 512]);
  };
  stage(0, 0);
  __syncthreads();
  int cur = 0;
  for (int kt = 0; kt < nt; ++kt) {
    if (kt + 1 < nt) stage(kt + 1, cur ^ 1);
    bf16x8 af[4], bfr[4];
    #pragma unroll
    for (int i = 0; i < 4; i++)
      af[i] = *(const bf16x8*)&Als[cur][(wr * 64 + i * 16 + lr) * 32 + lk * 8];
    #pragma unroll
    for (int j = 0; j < 4; j++)
      bfr[j] = *(const bf16x8*)&Bls[cur][(wc * 64 + j * 16 + lr) * 32 + lk * 8];
    #pragma unroll
    for (int i = 0; i < 4; i++)
      #pragma unroll
      for (int j = 0; j < 4; j++)
        acc[i][j] = __builtin_amdgcn_mfma_f32_16x16x32_bf16(af[i], bfr[j], acc[i][j], 0, 0, 0);
    __syncthreads();
    cur ^= 1;
  }
  #pragma unroll
  for (int i = 0; i < 4; i++)
    #pragma unroll
    for (int j = 0; j < 4; j++)
      #pragma unroll
      for (int g = 0; g < 4; g++) {
        int r = row0 + wr * 64 + i * 16 + lk * 4 + g;
        int c = col0 + wc * 64 + j * 16 + lr;
        float v = acc[i][j][g];
        void* dst = Cv;
        int cc = c, ld = ldc;
        if (c >= csplit) { dst = Cv2; cc = c - csplit; ld = ldc2; }
        size_t idx = (size_t)r * ld + cc;
        if (EPI == 0)      ((float*)dst)[idx] = v;
        else if (EPI == 1) ((__hip_bfloat16*)dst)[idx] = __float2bfloat16(v);
        else if (EPI == 2) {
          float xv = v + bias[cc];
          float gl = 0.5f * xv * (1.0f + erff(xv * 0.70710678118654752f));
          ((__hip_bfloat16*)dst)[idx] = __float2bfloat16(gl);
        } else {
          float s = 1.0f / (float)((r & (TDIM - 1)) + 1);
          ((float*)dst)[idx] = v * s;
        }
      }
}

// ================= 256^2 pipelined engine (big GEMMs) =================
// BM=BN=256, BK=32, 8 waves (2M x 4N), 4-deep LDS ring (128 KiB), counted vmcnt(8),
// 2 phases/iter {8 ds_read_b128 | 2 gload_lds | barrier | setprio(1) 16 MFMA setprio(0) | barrier},
// LDS slot-swizzle slot^=(row>>1)&3 via pre-swizzled global source (involution both sides).
template<int EPI>
__global__ __launch_bounds__(512, 2) void gemm_nt_256(const __hip_bfloat16* __restrict__ A,
    const __hip_bfloat16* __restrict__ B, void* __restrict__ Cv, void* __restrict__ Cv2,
    int csplit, int ldc, int ldc2, const float* __restrict__ bias, int M, int N, int Kd) {
  __shared__ __align__(16) short Als[4][256 * 32];   // 64 KB
  __shared__ __align__(16) short Bls[4][256 * 32];   // 64 KB

  int nbx = gridDim.x;
  int nwg = nbx * gridDim.y;
  int bx = blockIdx.x, by = blockIdx.y;
  if ((nwg & 7) == 0) {
    int orig = by * nbx + bx;
    int cpx = nwg >> 3;
    int id = (orig & 7) * cpx + (orig >> 3);
    bx = id % nbx; by = id / nbx;
  }
  const short* As = (const short*)A;
  const short* Bs = (const short*)B;
  const int t  = threadIdx.x;      // 0..511
  const int w  = t >> 6;           // 0..7
  const int l  = t & 63;
  const int lr = l & 15;
  const int lk = l >> 4;
  const int wr = w >> 2;           // 0..1 (M half)
  const int wc = w & 3;            // 0..3 (N quarter)
  const int row0 = by * 256;
  const int col0 = bx * 256;

  // ---- staging map: thread t covers LDS linear bytes [c*8192 + t*16), c=chunk(0..1) ----
  // logical row = c*128 + t/4, linear slot = t&3; source col-slot = slot ^ ((row>>1)&3)
  const int srow  = t >> 2;                       // 0..127
  const int sslot = (t & 3) ^ ((srow >> 1) & 3);  // same for row and row+128 (128>>1 ≡ 0 mod 4)
  const short* agA0 = As + (size_t)(row0 + srow) * Kd + sslot * 8;
  const short* agA1 = As + (size_t)(row0 + 128 + srow) * Kd + sslot * 8;
  const short* bgB0 = Bs + (size_t)(col0 + srow) * Kd + sslot * 8;
  const short* bgB1 = Bs + (size_t)(col0 + 128 + srow) * Kd + sslot * 8;

  auto stage2A = [&](int kt3) {
    int k0 = kt3 << 5;
    short* base = &Als[kt3 & 3][0];
    gload16(agA0 + k0, base + w * 512);
    gload16(agA1 + k0, base + 4096 + w * 512);
  };
  auto stage2B = [&](int kt3) {
    int k0 = kt3 << 5;
    short* base = &Bls[kt3 & 3][0];
    gload16(bgB0 + k0, base + w * 512);
    gload16(bgB1 + k0, base + 4096 + w * 512);
  };

  // ---- fragment LDS offsets (shorts), swizzled; constant across iterations ----
  int aoff[8], boff[4];
  #pragma unroll
  for (int mf = 0; mf < 8; ++mf) {
    int r = wr * 128 + mf * 16 + lr;
    aoff[mf] = r * 32 + ((lk ^ ((r >> 1) & 3)) << 3);
  }
  #pragma unroll
  for (int nf = 0; nf < 4; ++nf) {
    int r = wc * 64 + nf * 16 + lr;
    boff[nf] = r * 32 + ((lk ^ ((r >> 1) & 3)) << 3);
  }

  f32x4 acc[8][4] = {};
  const int NT = Kd >> 5;

  // ---- prologue: stage tiles 0..2 (12 loads/thread), wait tile 0 (vmcnt 8 = tiles 1,2 in flight) ----
  stage2A(0); stage2B(0);
  stage2A(1); stage2B(1);
  stage2A(2); stage2B(2);
  asm volatile("s_waitcnt vmcnt(8)" ::: "memory");
  __builtin_amdgcn_sched_barrier(0);
  __builtin_amdgcn_s_barrier();

  for (int kt = 0; kt < NT; ++kt) {
    const short* Ab = &Als[kt & 3][0];
    const short* Bb = &Bls[kt & 3][0];
    const bool st = (kt + 3 < NT);
    // ---- phase 0: A-frags 0..3 + all B-frags; stage A of kt+3; 16 MFMA ----
    bf16x8 af[4], bfr[4];
    #pragma unroll
    for (int mf = 0; mf < 4; ++mf) af[mf] = *(const bf16x8*)&Ab[aoff[mf]];
    #pragma unroll
    for (int nf = 0; nf < 4; ++nf) bfr[nf] = *(const bf16x8*)&Bb[boff[nf]];
    if (st) stage2A(kt + 3);
    __builtin_amdgcn_s_barrier();
    __builtin_amdgcn_s_setprio(1);
    #pragma unroll
    for (int mf = 0; mf < 4; ++mf)
      #pragma unroll
      for (int nf = 0; nf < 4; ++nf)
        acc[mf][nf] = __builtin_amdgcn_mfma_f32_16x16x32_bf16(af[mf], bfr[nf], acc[mf][nf], 0, 0, 0);
    __builtin_amdgcn_s_setprio(0);
    __builtin_amdgcn_s_barrier();
    // ---- phase 1: A-frags 4..7 (B reused in regs); stage B of kt+3; 16 MFMA ----
    bf16x8 ag[4];
    #pragma unroll
    for (int mf = 0; mf < 4; ++mf) ag[mf] = *(const bf16x8*)&Ab[aoff[4 + mf]];
    if (st) stage2B(kt + 3);
    __builtin_amdgcn_s_barrier();
    __builtin_amdgcn_s_setprio(1);
    #pragma unroll
    for (int mf = 0; mf < 4; ++mf)
      #pragma unroll
      for (int nf = 0; nf < 4; ++nf)
        acc[4 + mf][nf] = __builtin_amdgcn_mfma_f32_16x16x32_bf16(ag[mf], bfr[nf], acc[4 + mf][nf], 0, 0, 0);
    __builtin_amdgcn_s_setprio(0);
    // ---- iteration-end wait: tile kt+1 fully landed; never drain below the prefetch depth ----
    if (kt + 3 < NT)      { asm volatile("s_waitcnt vmcnt(8)" ::: "memory"); }
    else if (kt + 2 < NT) { asm volatile("s_waitcnt vmcnt(4)" ::: "memory"); }
    else if (kt + 1 < NT) { asm volatile("s_waitcnt vmcnt(0)" ::: "memory"); }
    __builtin_amdgcn_sched_barrier(0);
    __builtin_amdgcn_s_barrier();
  }

  #pragma unroll
  for (int mf = 0; mf < 8; ++mf)
    #pragma unroll
    for (int nf = 0; nf < 4; ++nf)
      #pragma unroll
      for (int g = 0; g < 4; ++g) {
        int r = row0 + wr * 128 + mf * 16 + lk * 4 + g;
        int c = col0 + wc * 64 + nf * 16 + lr;
        float v = acc[mf][nf][g];
        void* dst = Cv;
        int cc = c, ld = ldc;
        if (c >= csplit) { dst = Cv2; cc = c - csplit; ld = ldc2; }
        size_t idx = (size_t)r * ld + cc;
        if (EPI == 0)      ((float*)dst)[idx] = v;
        else if (EPI == 1) ((__hip_bfloat16*)dst)[idx] = __float2bfloat16(v);
        else if (EPI == 2) {
          float xv = v + bias[cc];
          float gl = 0.5f * xv * (1.0f + erff(xv * 0.70710678118654752f));
          ((__hip_bfloat16*)dst)[idx] = __float2bfloat16(gl);
        } else {  // EPI == 4: divide by n_valid, f32 out
          float s = 1.0f / (float)((r & (TDIM - 1)) + 1);
          ((float*)dst)[idx] = v * s;
        }
      }
}

// ---------------- router ----------------
__global__ __launch_bounds__(256) void router_kernel(const __hip_bfloat16* __restrict__ H,
    const float* __restrict__ w2, const float* __restrict__ b2,
    const float* __restrict__ ebias, float* __restrict__ wgt) {
  int wv = threadIdx.x >> 6;
  int l  = threadIdx.x & 63;
  int row = blockIdx.x * 4 + wv;
  if (row >= BT) return;
  float acc[KEXPN] = {};
  for (int i = 0; i < BDIM / 64; i++) {
    int h = i * 64 + l;
    float hv = __bfloat162float(H[(size_t)row * BDIM + h]);
    #pragma unroll
    for (int k = 0; k < KEXPN; k++) acc[k] += hv * w2[k * BDIM + h];
  }
  #pragma unroll
  for (int k = 0; k < KEXPN; k++)
    for (int off = 32; off; off >>= 1) acc[k] += __shfl_down(acc[k], off);
  if (l == 0) {
    float lg[KEXPN];
    float mx = -1e30f;
    #pragma unroll
    for (int k = 0; k < KEXPN; k++) { lg[k] = acc[k] + b2[k] + ebias[k]; mx = fmaxf(mx, lg[k]); }
    float s = 0.0f;
    #pragma unroll
    for (int k = 0; k < KEXPN; k++) { lg[k] = expf(lg[k] - mx); s += lg[k]; }
    float inv = 1.0f / s;
    #pragma unroll
    for (int k = 0; k < KEXPN; k++) wgt[(size_t)row * KEXPN + k] = lg[k] * inv;
  }
}

// ---------------- cumsum phase 1 ----------------
__global__ __launch_bounds__(1024) void chunksum_kernel(const float* __restrict__ yW,
    float* __restrict__ S) {
  int j  = threadIdx.x;
  int ch = blockIdx.x;
  int b  = blockIdx.y;
  size_t base = ((size_t)b * TDIM + ch * TC) * KRC + j;
  float s = 0.0f;
  for (int t = 0; t < TC; t++) s += yW[base + (size_t)t * KRC];
  S[((size_t)b * NCH + ch) * KRC + j] = s;
}

// ---------------- cumsum phase 2 ----------------
__global__ __launch_bounds__(1024) void scan_chunks_kernel(float* __restrict__ S) {
  int j = threadIdx.x;
  int b = blockIdx.x;
  float run = 0.0f;
  for (int ch = 0; ch < NCH; ch++) {
    size_t i = ((size_t)b * NCH + ch) * KRC + j;
    float v = S[i];
    S[i] = run;
    run += v;
  }
}

// ---------------- cumsum phase 3 + combine both branches -> Pcat ----------------
__global__ __launch_bounds__(1024) void combine_kernel(const float* __restrict__ yW,
    const float* __restrict__ S, const __hip_bfloat16* __restrict__ xV,
    const float* __restrict__ wf, const float* __restrict__ wi,
    const float* __restrict__ alphaPtr, __hip_bfloat16* __restrict__ P) {
  int j  = threadIdx.x;
  int ch = blockIdx.x;
  int b  = blockIdx.y;
  float alpha = alphaPtr[0];
  float scale = (j < KR) ? 1.0f : alpha;
  const float* wgt = (j < KR) ? wf : wi;
  int k = (j & (KR - 1)) >> 6;
  int pcol = (j < KR) ? j : j + 128;
  float run = S[((size_t)b * NCH + ch) * KRC + j];
  for (int t0 = 0; t0 < TC; t0++) {
    size_t row = (size_t)b * TDIM + ch * TC + t0;
    run += yW[row * KRC + j];
    float p = __bfloat162float(xV[row * KRC + j]) * run * wgt[row * KEXPN + k] * scale;
    P[row * PW + pcol] = __float2bfloat16(p);
  }
}

// ---------------- fill extension columns of Pcat ----------------
__global__ __launch_bounds__(256) void extfill_kernel(__hip_bfloat16* __restrict__ P,
    const float* __restrict__ wf, const float* __restrict__ wi,
    const float* __restrict__ alphaPtr) {
  int id = blockIdx.x * 256 + threadIdx.x;   // BT*256
  int row = id >> 8, j = id & 255;
  if (row >= BT) return;
  float alpha = alphaPtr[0];
  int half = j >> 7;
  int jj = j & 127;
  int col = half ? (KC + KR + jj) : (KR + jj);
  const float* wgt = half ? wi : wf;
  float sc = half ? alpha : 1.0f;
  float v = (jj < KEXPN) ? wgt[(size_t)row * KEXPN + jj] * sc : 0.0f;
  P[(size_t)row * PW + col] = __float2bfloat16(v);
}

// ---------------- sentinel ----------------
__global__ __launch_bounds__(256) void fill_kernel(float* __restrict__ out, long n, float val) {
  long id = (long)blockIdx.x * 256 + threadIdx.x;
  if (id < n) out[id] = val;
}

extern "C" void kernel_launch(void* const* d_in, const int* in_sizes, int n_in,
                              void* d_out, int out_size, void* d_ws, size_t ws_size,
                              hipStream_t stream) {
  const float* x        = (const float*)d_in[0];
  const float* W_Q      = (const float*)d_in[1];
  const float* W_K      = (const float*)d_in[2];
  const float* W_O      = (const float*)d_in[3];
  const float* W_inv    = (const float*)d_in[4];
  const float* V_fwd    = (const float*)d_in[5];
  const float* W_fwd    = (const float*)d_in[6];
  const float* U_fwd    = (const float*)d_in[7];
  const float* b_fwd    = (const float*)d_in[8];
  const float* V_inv    = (const float*)d_in[9];
  const float* W_inv_e  = (const float*)d_in[10];
  const float* U_inv    = (const float*)d_in[11];
  const float* b_inv    = (const float*)d_in[12];
  const float* rw1      = (const float*)d_in[13];
  const float* rb1      = (const float*)d_in[14];
  const float* rw2      = (const float*)d_in[15];
  const float* rb2      = (const float*)d_in[16];
  const float* alphaPtr = (const float*)d_in[17];
  const float* ebias    = (const float*)d_in[18];

  char* ws = (char*)d_ws;
  size_t off = 0;
  auto alloc = [&](size_t sz) -> void* {
    void* p = ws + off;
    off += (sz + 255) & ~(size_t)255;
    return p;
  };

  void* wqk   = alloc((size_t)2 * BDIM * BDIM * 2); // [W_Q rows | W_K rows]
  void* w1p   = alloc((size_t)2 * BDIM * BDIM * 2); // [w1 rows | w1i rows]
  void* wo    = alloc((size_t)BDIM * BDIM * 2);
  void* winvT = alloc((size_t)BDIM * BDIM * 2);
  void* vmq   = alloc((size_t)KRC * BDIM * 2);      // rows 0-511 vm_f, 512-1023 Gq
  void* wmG   = alloc((size_t)KRC * BDIM * 2);      // rows 0-511 wm_f, 512-1023 Gk
  void* vm_ie = alloc((size_t)KR * BDIM * 2);
  void* vm_i  = alloc((size_t)KR * BDIM * 2);
  void* utTf  = alloc((size_t)KC * BDIM * 2);
  void* utTi  = alloc((size_t)KC * BDIM * 2);
  void* Mcat  = alloc((size_t)BDIM * PW * 2);
  void* wgt_f = alloc((size_t)BT * KEXPN * 4);
  void* wgt_i = alloc((size_t)BT * KEXPN * 4);
  void* S     = alloc((size_t)4 * NCH * KRC * 4);
  void* s_Q   = alloc((size_t)BT * BDIM * 2);
  void* s_K   = alloc((size_t)BT * BDIM * 2);
  void* s_x   = alloc((size_t)BT * BDIM * 2);
  void* s_yW  = alloc((size_t)BT * KRC * 4);
  void* Hf    = s_x;
  void* Hi    = s_yW;
  void* xVcat = s_x;
  void* Pcat  = s_Q;

  if (off > ws_size) {
    fill_kernel<<<dim3((unsigned)((out_size + 255) / 256)), 256, 0, stream>>>(
        (float*)d_out, (long)out_size, (float)(off >> 20));
    return;
  }

  __hip_bfloat16* wq  = (__hip_bfloat16*)wqk;
  __hip_bfloat16* wk  = wq + (size_t)BDIM * BDIM;
  __hip_bfloat16* w1  = (__hip_bfloat16*)w1p;
  __hip_bfloat16* w1i = w1 + (size_t)BDIM * BDIM;
  __hip_bfloat16* Gq  = (__hip_bfloat16*)vmq + (size_t)KR * BDIM;
  __hip_bfloat16* Gk  = (__hip_bfloat16*)wmG + (size_t)KR * BDIM;

  auto cvt = [&](const float* in, void* out, long n) {
    long n4 = n / 4;
    cvt_bf16_kernel<<<dim3((unsigned)((n4 + 255) / 256)), dim3(256), 0, stream>>>(
        in, (__hip_bfloat16*)out, n4);
  };
  // 128^2 engine (folds)
  auto gemm2s = [&](const void* A, const void* Bm, void* C, void* C2, int csplit,
                    int ldc, int ldc2, int M, int N, int Kd, int epi, const float* bias) {
    dim3 g(N / 128, M / 128);
    if (epi == 0)      gemm_nt<0><<<g, 256, 0, stream>>>((const __hip_bfloat16*)A, (const __hip_bfloat16*)Bm, C, C2, csplit, ldc, ldc2, bias, M, N, Kd);
    else if (epi == 1) gemm_nt<1><<<g, 256, 0, stream>>>((const __hip_bfloat16*)A, (const __hip_bfloat16*)Bm, C, C2, csplit, ldc, ldc2, bias, M, N, Kd);
    else if (epi == 2) gemm_nt<2><<<g, 256, 0, stream>>>((const __hip_bfloat16*)A, (const __hip_bfloat16*)Bm, C, C2, csplit, ldc, ldc2, bias, M, N, Kd);
    else               gemm_nt<4><<<g, 256, 0, stream>>>((const __hip_bfloat16*)A, (const __hip_bfloat16*)Bm, C, C2, csplit, ldc, ldc2, bias, M, N, Kd);
  };
  auto gemms = [&](const void* A, const void* Bm, void* C, int M, int N, int Kd,
                   int epi, const float* bias) {
    gemm2s(A, Bm, C, C, N, N, N, M, N, Kd, epi, bias);
  };
  // 256^2 pipelined engine (big GEMMs; M,N multiples of 256, K multiple of 32, K/32 >= 4)
  auto gemm2b = [&](const void* A, const void* Bm, void* C, void* C2, int csplit,
                    int ldc, int ldc2, int M, int N, int Kd, int epi, const float* bias) {
    dim3 g(N / 256, M / 256);
    if (epi == 0)      gemm_nt_256<0><<<g, 512, 0, stream>>>((const __hip_bfloat16*)A, (const __hip_bfloat16*)Bm, C, C2, csplit, ldc, ldc2, bias, M, N, Kd);
    else if (epi == 1) gemm_nt_256<1><<<g, 512, 0, stream>>>((const __hip_bfloat16*)A, (const __hip_bfloat16*)Bm, C, C2, csplit, ldc, ldc2, bias, M, N, Kd);
    else if (epi == 2) gemm_nt_256<2><<<g, 512, 0, stream>>>((const __hip_bfloat16*)A, (const __hip_bfloat16*)Bm, C, C2, csplit, ldc, ldc2, bias, M, N, Kd);
    else               gemm_nt_256<4><<<g, 512, 0, stream>>>((const __hip_bfloat16*)A, (const __hip_bfloat16*)Bm, C, C2, csplit, ldc, ldc2, bias, M, N, Kd);
  };
  auto gemmb = [&](const void* A, const void* Bm, void* C, int M, int N, int Kd,
                   int epi, const float* bias) {
    gemm2b(A, Bm, C, C, N, N, N, M, N, Kd, epi, bias);
  };

  // ---- conversions & packing ----
  cvt(x,   s_x, (long)BT * BDIM);
  cvt(W_Q, wq,  (long)BDIM * BDIM);
  cvt(W_K, wk,  (long)BDIM * BDIM);
  cvt(W_O, wo,  (long)BDIM * BDIM);
  cvt(rw1, w1,  (long)BDIM * BDIM);
  {
    dim3 gt((BDIM * BDIM + 255) / 256);
    transpose_pack_kernel<<<gt, 256, 0, stream>>>(W_inv, (__hip_bfloat16*)winvT);
    dim3 g((KR * BDIM + 255) / 256);
    pack_vmat_kernel<<<g, 256, 0, stream>>>(V_fwd,   (__hip_bfloat16*)vmq);
    pack_vmat_kernel<<<g, 256, 0, stream>>>(W_fwd,   (__hip_bfloat16*)wmG);
    pack_vmat_kernel<<<g, 256, 0, stream>>>(W_inv_e, (__hip_bfloat16*)vm_ie);
    pack_vmat_kernel<<<g, 256, 0, stream>>>(V_inv,   (__hip_bfloat16*)vm_i);
    dim3 gu((KC * BDIM + 255) / 256);
    pack_utT_kernel<<<gu, 256, 0, stream>>>(U_fwd, b_fwd, (__hip_bfloat16*)utTf);
    pack_utT_kernel<<<gu, 256, 0, stream>>>(U_inv, b_inv, (__hip_bfloat16*)utTi);
  }

  // ---- weight folds (128^2 engine) ----
  gemms(w1,    winvT, w1i, BDIM, BDIM, BDIM, 1, nullptr);
  gemms(vm_ie, winvT, Gq,  KR,   BDIM, BDIM, 1, nullptr);
  gemms(vm_i,  winvT, Gk,  KR,   BDIM, BDIM, 1, nullptr);
  gemm2s(wo, utTf, Mcat, Mcat, KC, PW, PW, BDIM, KC, BDIM, 1, nullptr);
  gemm2s(wo, utTi, (__hip_bfloat16*)Mcat + KC, (__hip_bfloat16*)Mcat + KC,
         KC, PW, PW, BDIM, KC, BDIM, 1, nullptr);

  // ---- fused Q|K projection ----
  gemm2b(s_x, wqk, s_Q, s_K, BDIM, BDIM, BDIM, BT, 2 * BDIM, BDIM, 1, nullptr);

  // ---- fused H ----
  gemm2b(s_Q, w1p, Hf, Hi, BDIM, BDIM, BDIM, BT, 2 * BDIM, BDIM, 2, rb1);
  router_kernel<<<dim3(BT / 4), 256, 0, stream>>>((const __hip_bfloat16*)Hf, rw2, rb2, ebias, (float*)wgt_f);
  router_kernel<<<dim3(BT / 4), 256, 0, stream>>>((const __hip_bfloat16*)Hi, rw2, rb2, ebias, (float*)wgt_i);

  // ---- fused branch GEMMs ----
  gemmb(s_Q, vmq, xVcat, BT, KRC, BDIM, 1, nullptr);
  gemmb(s_K, wmG, s_yW,  BT, KRC, BDIM, 0, nullptr);

  // ---- causal cumsum + combine into Pcat ----
  dim3 gch(NCH, 4);
  chunksum_kernel<<<gch, 1024, 0, stream>>>((const float*)s_yW, (float*)S);
  scan_chunks_kernel<<<dim3(4), 1024, 0, stream>>>((float*)S);
  combine_kernel<<<gch, 1024, 0, stream>>>((const float*)s_yW, (const float*)S,
      (const __hip_bfloat16*)xVcat, (const float*)wgt_f, (const float*)wgt_i,
      alphaPtr, (__hip_bfloat16*)Pcat);
  extfill_kernel<<<dim3(BT * 256 / 256), 256, 0, stream>>>((__hip_bfloat16*)Pcat,
      (const float*)wgt_f, (const float*)wgt_i, alphaPtr);

  // ---- single output GEMM: out = diag(1/n) * Pcat @ Mcat^T ----
  gemmb(Pcat, Mcat, d_out, BT, BDIM, PW, 4, nullptr);
}